// Round 16
// baseline (6929.388 us; speedup 1.0000x reference)
//
#include <hip/hip_runtime.h>
#include <math.h>

#define B 128
#define LATENT 512
#define H 1024
#define BH (B * H)

typedef unsigned short ushort_t;
typedef unsigned int uint_t;
typedef __bf16 bf16x8 __attribute__((ext_vector_type(8)));
typedef float f32x4 __attribute__((ext_vector_type(4)));

#define AT_LD(p)    __hip_atomic_load((p), __ATOMIC_RELAXED, __HIP_MEMORY_SCOPE_AGENT)
#define AT_ST(p, v) __hip_atomic_store((p), (v), __ATOMIC_RELAXED, __HIP_MEMORY_SCOPE_AGENT)

// ---------------- common small kernels ----------------

__global__ __launch_bounds__(256) void zero4_kernel(float4* __restrict__ p, int n4) {
  int i = blockIdx.x * blockDim.x + threadIdx.x;
  int stride = gridDim.x * blockDim.x;
  float4 z = {0.f, 0.f, 0.f, 0.f};
  for (; i < n4; i += stride) p[i] = z;
}

__device__ __forceinline__ void split_bf16(float f, ushort_t& h, ushort_t& l) {
  uint_t u = __float_as_uint(f);
  uint_t hb = (u + 0x7FFFu + ((u >> 16) & 1u)) >> 16;
  float fh = __uint_as_float(hb << 16);
  float r = f - fh;
  uint_t v = __float_as_uint(r);
  uint_t lb = (v + 0x7FFFu + ((v >> 16) & 1u)) >> 16;
  h = (ushort_t)hb; l = (ushort_t)lb;
}

__global__ __launch_bounds__(256) void split_kernel(const float* __restrict__ src,
                                                    ushort_t* __restrict__ hi,
                                                    ushort_t* __restrict__ lo, int n) {
  int i = blockIdx.x * blockDim.x + threadIdx.x;
  int stride = gridDim.x * blockDim.x;
  for (; i < n; i += stride) {
    ushort_t h, l;
    split_bf16(src[i], h, l);
    hi[i] = h; lo[i] = l;
  }
}

__global__ __launch_bounds__(256) void split_hi_kernel(const float* __restrict__ src,
                                                       ushort_t* __restrict__ hi, int n) {
  int i = blockIdx.x * blockDim.x + threadIdx.x;
  int stride = gridDim.x * blockDim.x;
  for (; i < n; i += stride) {
    uint_t u = __float_as_uint(src[i]);
    hi[i] = (ushort_t)((u + 0x7FFFu + ((u >> 16) & 1u)) >> 16);
  }
}

// wf = wih0 @ w2  (fp32 GEMM, hi split)
__global__ __launch_bounds__(256) void wf_kernel(const float* __restrict__ wih0,
                                                 const float* __restrict__ w2,
                                                 ushort_t* __restrict__ wfh) {
  __shared__ float As[32][33];
  __shared__ float Bs[32][33];
  const int i0 = blockIdx.x * 32;
  const int k0 = blockIdx.y * 32;
  const int tid = threadIdx.x;
  const int r = tid >> 3, c4 = (tid & 7) << 2;
  float acc[4] = {0.f, 0.f, 0.f, 0.f};
  for (int m0 = 0; m0 < LATENT; m0 += 32) {
    {
      const float4 v = *reinterpret_cast<const float4*>(&wih0[(size_t)(i0 + r) * LATENT + m0 + c4]);
      As[r][c4] = v.x; As[r][c4 + 1] = v.y; As[r][c4 + 2] = v.z; As[r][c4 + 3] = v.w;
      const float4 w = *reinterpret_cast<const float4*>(&w2[(size_t)(m0 + r) * H + k0 + c4]);
      Bs[r][c4] = w.x; Bs[r][c4 + 1] = w.y; Bs[r][c4 + 2] = w.z; Bs[r][c4 + 3] = w.w;
    }
    __syncthreads();
    #pragma unroll
    for (int mm = 0; mm < 32; ++mm) {
      const float a = As[r][mm];
      #pragma unroll
      for (int x = 0; x < 4; ++x) acc[x] = fmaf(a, Bs[mm][c4 + x], acc[x]);
    }
    __syncthreads();
  }
  #pragma unroll
  for (int x = 0; x < 4; ++x) {
    uint_t u = __float_as_uint(acc[x]);
    wfh[(size_t)(i0 + r) * H + k0 + c4 + x] =
        (ushort_t)((u + 0x7FFFu + ((u >> 16) & 1u)) >> 16);
  }
}

// bf0[g] = bih0[g] + dot(wih0[g,:], bp2)
__global__ __launch_bounds__(256) void bias_fuse_kernel(const float* __restrict__ wih0,
                                                        const float* __restrict__ bp2,
                                                        const float* __restrict__ bih0,
                                                        float* __restrict__ bf0) {
  int g = blockIdx.x * blockDim.x + threadIdx.x;
  if (g < 3 * H) {
    float s = bih0[g];
    const float* row = wih0 + (size_t)g * LATENT;
    #pragma unroll 4
    for (int l = 0; l < LATENT; ++l) s = fmaf(row[l], bp2[l], s);
    bf0[g] = s;
  }
}

__device__ __forceinline__ float sigmoidf_(float v) { return 1.0f / (1.0f + expf(-v)); }

// ---------------- RELAXED grid barrier: no acq/rel -> no per-phase L2 inv/wb ----------------
// Coherence of cross-phase data handled explicitly by agent-scope atomic ld/st.
__device__ __forceinline__ void grid_barrier(unsigned* bar, int tid, int bid) {
  __syncthreads();   // drains vmcnt: all this block's stores complete before arrival
  if (tid == 0) {
    const int g = bid & 7;
    unsigned* arr    = bar + (g << 6);
    unsigned* rel    = bar + 1024 + (g << 6);
    unsigned* master = bar + 2048;
    unsigned gen = AT_LD(rel);
    unsigned a = __hip_atomic_fetch_add(arr, 1u, __ATOMIC_RELAXED, __HIP_MEMORY_SCOPE_AGENT);
    if (a == 31u) {
      AT_ST(arr, 0u);
      unsigned m = __hip_atomic_fetch_add(master, 1u, __ATOMIC_RELAXED, __HIP_MEMORY_SCOPE_AGENT);
      if (m == 7u) {
        AT_ST(master, 0u);
        #pragma unroll
        for (int i = 0; i < 8; ++i)
          __hip_atomic_fetch_add(bar + 1024 + (i << 6), 1u, __ATOMIC_RELAXED, __HIP_MEMORY_SCOPE_AGENT);
      }
    }
    while (AT_LD(rel) == gen)
      __builtin_amdgcn_s_sleep(1);
  }
  __syncthreads();
}

// ---------------- one GEMM phase: 32 rows x NJ*16 cols x NG gates ----------------
// W slots: cached global_load_lds (L2-resident across phases). A slots (cross-phase
// h/p state): agent-scope atomic reg loads (coherence-point reads, bypass stale L2)
// + ds_write_b128, issue-early/write-late inside the double buffer.
template <int NJ, int NG, int PH, int EPI, bool WLO, int CHUNKW>
__device__ __forceinline__ void phase_mm(
    char* smem, const int tid, const int Mb, const int jb, const bool active,
    const ushort_t* aAh, const ushort_t* aAl, int aApitch, int K1,
    const ushort_t* wAh, const ushort_t* wAl,
    const ushort_t* aBh, const ushort_t* aBl, int aBpitch, int K2,
    const ushort_t* wBh,
    const float* bih, const float* bhh,
    const float* h_prev, float* h_out,
    ushort_t* out_hi, ushort_t* out_lo, int split_pitch,
    const float* bias, float* out_f32)
{
  if (!active) return;
  constexpr int KST = CHUNKW / 128;
  constexpr int SLOTB = CHUNKW * 32;
  constexpr int NW = NJ * NG;
  constexpr int NSLOTA = 4 + NW * (WLO ? 2 : 1);
  constexpr int NSLOTB = 4 + NW;
  constexpr int BUFB = NSLOTA * SLOTB;
  constexpr int NPG = PH * NW;
  constexpr int CW = NJ * 16;
  constexpr int CSHIFT = (CHUNKW == 256) ? 8 : 7;

  const int b0 = Mb * 32;
  const int j0 = jb * CW;
  const int NC1 = K1 >> CSHIFT;
  const int NC2 = (PH == 2) ? (K2 >> CSHIFT) : 0;
  const int NC = NC1 + NC2;

  const char* g[NSLOTA];
  auto build = [&](const ushort_t* ah, const ushort_t* al, int apitch,
                   const ushort_t* wh, const ushort_t* wl, int K) {
    const int rowt = tid >> 4;
    const int cp = tid & 15;
    const int cc = cp ^ rowt;
    #pragma unroll
    for (int u = 0; u < NSLOTA; ++u) {
      const ushort_t* basep; size_t off;
      if (u < 2)      { basep = ah; off = (size_t)(b0 + u * 16 + rowt) * apitch + cc * 8; }
      else if (u < 4) { basep = al; off = (size_t)(b0 + (u - 2) * 16 + rowt) * apitch + cc * 8; }
      else if (u < 4 + NW) {
        const int w = u - 4, jt = w % NJ, gate = w / NJ;
        const int wrow = (NG == 3) ? (gate * H + j0 + jt * 16 + rowt) : (j0 + jt * 16 + rowt);
        basep = wh; off = (size_t)wrow * K + cc * 8;
      } else {
        const int w = u - 4 - NW, jt = w % NJ, gate = w / NJ;
        const int wrow = (NG == 3) ? (gate * H + j0 + jt * 16 + rowt) : (j0 + jt * 16 + rowt);
        basep = (wl != nullptr) ? wl : wh; off = (size_t)wrow * K + cc * 8;
      }
      g[u] = (const char*)(basep + off);
    }
  };

  // fragment read offsets per k-substep
  const int s = tid >> 6;
  const int q = (tid >> 4) & 3;
  const int r = tid & 15;
  int gsv[KST];
  #pragma unroll
  for (int k2 = 0; k2 < KST; ++k2) {
    const int G = s * (4 * KST) + k2 * 4 + q;
    gsv[k2] = (G >> 4) * 4096 + ((G & 15) ^ r) * 16;
  }
  const int rbase = r * 256;

  f32x4 accA[NJ][NG][2];
  f32x4 accB[NJ][NG][2];
  #pragma unroll
  for (int jt = 0; jt < NJ; ++jt)
    #pragma unroll
    for (int gg = 0; gg < NG; ++gg)
      #pragma unroll
      for (int mf = 0; mf < 2; ++mf) {
        accA[jt][gg][mf] = (f32x4){0.f, 0.f, 0.f, 0.f};
        accB[jt][gg][mf] = (f32x4){0.f, 0.f, 0.f, 0.f};
      }

  const unsigned wofs = (unsigned)(tid >> 6) * 1024;
  auto issueW = [&](int bsel, int koff, int nslot) {
    #pragma unroll
    for (int u = 4; u < NSLOTA; ++u) {
      if (u < nslot) {
        #pragma unroll
        for (int j = 0; j < KST; ++j) {
          __builtin_amdgcn_global_load_lds(
              (const __attribute__((address_space(1))) void*)(g[u] + koff + j * 256),
              (__attribute__((address_space(3))) void*)(smem + bsel * BUFB + u * SLOTB + j * 4096 + wofs),
              16, 0, 0);
        }
      }
    }
  };

  uint4 aReg[4][KST];
  auto loadA = [&](int koff) {
    #pragma unroll
    for (int u = 0; u < 4; ++u)
      #pragma unroll
      for (int j = 0; j < KST; ++j) {
        uint_t* p = (uint_t*)(void*)(g[u] + koff + j * 256);
        aReg[u][j].x = AT_LD(p + 0);
        aReg[u][j].y = AT_LD(p + 1);
        aReg[u][j].z = AT_LD(p + 2);
        aReg[u][j].w = AT_LD(p + 3);
      }
  };
  auto writeA = [&](int bsel) {
    #pragma unroll
    for (int u = 0; u < 4; ++u)
      #pragma unroll
      for (int j = 0; j < KST; ++j)
        *(uint4*)(smem + bsel * BUFB + u * SLOTB + j * 4096 + tid * 16) = aReg[u][j];
  };

  auto computeA = [&](int bsel) {
    const char* base = smem + bsel * BUFB;
    #pragma unroll
    for (int k2 = 0; k2 < KST; ++k2) {
      const int fo = rbase + gsv[k2];
      bf16x8 ah0 = *(const bf16x8*)(base + 0 * SLOTB + fo);
      bf16x8 ah1 = *(const bf16x8*)(base + 1 * SLOTB + fo);
      bf16x8 al0 = *(const bf16x8*)(base + 2 * SLOTB + fo);
      bf16x8 al1 = *(const bf16x8*)(base + 3 * SLOTB + fo);
      #pragma unroll
      for (int gg = 0; gg < NG; ++gg)
        #pragma unroll
        for (int jt = 0; jt < NJ; ++jt) {
          const int w = gg * NJ + jt;
          bf16x8 wh = *(const bf16x8*)(base + (4 + w) * SLOTB + fo);
          accA[jt][gg][0] = __builtin_amdgcn_mfma_f32_16x16x32_bf16(ah0, wh, accA[jt][gg][0], 0, 0, 0);
          if (WLO) {
            bf16x8 wl = *(const bf16x8*)(base + (4 + NW + w) * SLOTB + fo);
            accA[jt][gg][0] = __builtin_amdgcn_mfma_f32_16x16x32_bf16(ah0, wl, accA[jt][gg][0], 0, 0, 0);
            accA[jt][gg][1] = __builtin_amdgcn_mfma_f32_16x16x32_bf16(ah1, wl, accA[jt][gg][1], 0, 0, 0);
          }
          accA[jt][gg][0] = __builtin_amdgcn_mfma_f32_16x16x32_bf16(al0, wh, accA[jt][gg][0], 0, 0, 0);
          accA[jt][gg][1] = __builtin_amdgcn_mfma_f32_16x16x32_bf16(ah1, wh, accA[jt][gg][1], 0, 0, 0);
          accA[jt][gg][1] = __builtin_amdgcn_mfma_f32_16x16x32_bf16(al1, wh, accA[jt][gg][1], 0, 0, 0);
        }
    }
  };
  auto computeB = [&](int bsel) {
    const char* base = smem + bsel * BUFB;
    #pragma unroll
    for (int k2 = 0; k2 < KST; ++k2) {
      const int fo = rbase + gsv[k2];
      bf16x8 ah0 = *(const bf16x8*)(base + 0 * SLOTB + fo);
      bf16x8 ah1 = *(const bf16x8*)(base + 1 * SLOTB + fo);
      bf16x8 al0 = *(const bf16x8*)(base + 2 * SLOTB + fo);
      bf16x8 al1 = *(const bf16x8*)(base + 3 * SLOTB + fo);
      #pragma unroll
      for (int gg = 0; gg < NG; ++gg)
        #pragma unroll
        for (int jt = 0; jt < NJ; ++jt) {
          const int w = gg * NJ + jt;
          bf16x8 wh = *(const bf16x8*)(base + (4 + w) * SLOTB + fo);
          accB[jt][gg][0] = __builtin_amdgcn_mfma_f32_16x16x32_bf16(ah0, wh, accB[jt][gg][0], 0, 0, 0);
          accB[jt][gg][0] = __builtin_amdgcn_mfma_f32_16x16x32_bf16(al0, wh, accB[jt][gg][0], 0, 0, 0);
          accB[jt][gg][1] = __builtin_amdgcn_mfma_f32_16x16x32_bf16(ah1, wh, accB[jt][gg][1], 0, 0, 0);
          accB[jt][gg][1] = __builtin_amdgcn_mfma_f32_16x16x32_bf16(al1, wh, accB[jt][gg][1], 0, 0, 0);
        }
    }
  };

  // prologue: chunk 0 fully staged
  build(aAh, aAl, aApitch, wAh, wAl, K1);
  issueW(0, 0, NSLOTA);
  loadA(0);
  writeA(0);

  #pragma unroll 1
  for (int c = 0; c < NC; ++c) {
    __syncthreads();   // chunk c staged (W vmcnt + A ds_writes drained)
    if (c + 1 < NC) {
      if (PH == 2 && c + 1 == NC1) {
        build(aBh, aBl, aBpitch, wBh, nullptr, K2);
        issueW((c + 1) & 1, 0, NSLOTB);
        loadA(0);
      } else {
        const bool isB = (PH == 2) && (c + 1 >= NC1);
        const int koff = (isB ? (c + 1 - NC1) : (c + 1)) * (CHUNKW * 2);
        issueW((c + 1) & 1, koff, isB ? NSLOTB : NSLOTA);
        loadA(koff);
      }
    }
    if (PH == 1 || c < NC1) computeA(c & 1);
    else                    computeB(c & 1);
    if (c + 1 < NC) writeA((c + 1) & 1);
  }
  __syncthreads();

  // ---- cross-wave reduce (alias smem) ----
  const int lane = tid & 63;
  #pragma unroll
  for (int gg = 0; gg < NG; ++gg)
    #pragma unroll
    for (int jt = 0; jt < NJ; ++jt)
      #pragma unroll
      for (int mf = 0; mf < 2; ++mf) {
        const int w = gg * NJ + jt;
        *(f32x4*)(smem + (size_t)(((s * NPG + w) * 2 + mf) * 64 + lane) * 16) = accA[jt][gg][mf];
        if (PH == 2)
          *(f32x4*)(smem + (size_t)(((s * NPG + NW + w) * 2 + mf) * 64 + lane) * 16) = accB[jt][gg][mf];
      }
  __syncthreads();

  for (int o = tid; o < 32 * CW; o += 256) {
    const int row = o / CW, c = o % CW;
    const int jt = c >> 4, cr = c & 15;
    const int mf = row >> 4, br = row & 15, qq = br >> 2, rg = br & 3;
    const int ln = cr + qq * 16;
    float v[PH * NG];
    #pragma unroll
    for (int pg = 0; pg < PH * NG; ++pg) {
      const int w = (pg < NG) ? (pg * NJ + jt) : (NW + (pg - NG) * NJ + jt);
      float sum = 0.f;
      #pragma unroll
      for (int ss = 0; ss < 4; ++ss)
        sum += *(const float*)(smem + (size_t)(((ss * NPG + w) * 2 + mf) * 64 + ln) * 16 + rg * 4);
      v[pg] = sum;
    }
    const int bglob = b0 + row, jglob = j0 + c;
    if (EPI == 0) {
      float ir = v[0] + bih[jglob];
      float iz = v[1] + bih[H + jglob];
      float in_ = v[2] + bih[2 * H + jglob];
      float hr = v[3] + bhh[jglob];
      float hz = v[4] + bhh[H + jglob];
      float hn = v[5] + bhh[2 * H + jglob];
      float rr_ = sigmoidf_(ir + hr);
      float zz_ = sigmoidf_(iz + hz);
      float nn_ = tanhf(in_ + rr_ * hn);
      float hp = AT_LD((float*)&h_prev[(size_t)bglob * H + jglob]);
      float ho = (1.f - zz_) * nn_ + zz_ * hp;
      AT_ST(&h_out[(size_t)bglob * H + jglob], ho);
      ushort_t hb, lb;
      split_bf16(ho, hb, lb);
      AT_ST(&out_hi[(size_t)bglob * H + jglob], hb);
      AT_ST(&out_lo[(size_t)bglob * H + jglob], lb);
    } else if (EPI == 1) {
      float vv = v[0] + bias[jglob];
      vv = fmaxf(vv, 0.f);
      ushort_t hb, lb;
      split_bf16(vv, hb, lb);
      AT_ST(&out_hi[(size_t)bglob * split_pitch + jglob], hb);
      AT_ST(&out_lo[(size_t)bglob * split_pitch + jglob], lb);
    } else {
      float vv = v[0] + bias[jglob];
      const int tt = bglob >> 7, bb2 = bglob & 127;
      out_f32[((size_t)bb2 * split_pitch + tt) * LATENT + jglob] = vv;
    }
  }
  __syncthreads();
}

// ---------------- persistent kernel: 65 enc + 192 dec phases ----------------

struct PParams {
  const ushort_t *ctxh, *ctxl;
  const ushort_t *wih0h, *whh0h;
  const ushort_t *wih1h, *whh1h;
  const ushort_t *w1h;
  const ushort_t *wfh;
  const float *bih0, *bhh0, *bih1, *bhh1, *bp1;
  const float *bf0;
  float *h0f0, *h0f1, *h1f0, *h1f1;
  ushort_t *h0hi0, *h0lo0, *h0hi1, *h0lo1;
  ushort_t *h1hi0, *h1lo0, *h1hi1, *h1lo1;
  ushort_t *h0Ahi, *h0Alo;
  unsigned* bar;
  int T_in, n_pred, ctx_pitch;
};

__global__ __launch_bounds__(256, 1) void gru_persistent(PParams P) {
  __shared__ char smem[114688];
  const int tid = threadIdx.x;
  const int bid = blockIdx.x;

  float* h0f[2] = {P.h0f0, P.h0f1};
  float* h1f[2] = {P.h1f0, P.h1f1};
  ushort_t* h0hi[2] = {P.h0hi0, P.h0hi1};
  ushort_t* h0lo[2] = {P.h0lo0, P.h0lo1};
  ushort_t* h1hi[2] = {P.h1hi0, P.h1hi1};
  ushort_t* h1lo[2] = {P.h1lo0, P.h1lo1};

  int p0 = 0, p1 = 0;

  // -------- pipelined encoder (CHUNKW=128) --------
  const int idx = (bid < 128) ? bid : (bid - 128);
  const int eMb = idx & 3;
  const int ejb = idx >> 2;
  #pragma unroll 1
  for (int p = 0; p <= P.T_in; ++p) {
    const int n0 = p0 ^ 1, n1 = p1 ^ 1;
    if (bid < 128) {
      if (p < P.T_in) {
        const int t = p;
        phase_mm<2, 3, 2, 0, false, 128>(smem, tid, eMb, ejb, true,
            P.ctxh + (size_t)t * LATENT, P.ctxl + (size_t)t * LATENT, P.ctx_pitch, LATENT,
            P.wih0h, nullptr,
            (t == 0) ? P.h0hi0 : P.h0Ahi + (size_t)(t - 1) * BH,
            (t == 0) ? P.h0lo0 : P.h0Alo + (size_t)(t - 1) * BH, H, H, P.whh0h,
            P.bih0, P.bhh0, h0f[p0], h0f[n0],
            P.h0Ahi + (size_t)t * BH, P.h0Alo + (size_t)t * BH, H, nullptr, nullptr);
      }
    } else {
      if (p >= 1) {
        const int t = p - 1;
        phase_mm<2, 3, 2, 0, false, 128>(smem, tid, eMb, ejb, true,
            P.h0Ahi + (size_t)t * BH, P.h0Alo + (size_t)t * BH, H, H,
            P.wih1h, nullptr,
            h1hi[p1], h1lo[p1], H, H, P.whh1h,
            P.bih1, P.bhh1, h1f[p1], h1f[n1],
            h1hi[n1], h1lo[n1], H, nullptr, nullptr);
      }
    }
    grid_barrier(P.bar, tid, bid);
    if (p < P.T_in) p0 = n0;
    if (p >= 1) p1 = n1;
  }

  // -------- decoder (CHUNKW=256): {D0 fused, D1, DP} --------
  const int dMb = bid & 3;
  const int djb = bid >> 2;
  const ushort_t* d0ph = P.h0Ahi + (size_t)(P.T_in - 1) * BH;
  const ushort_t* d0pl = P.h0Alo + (size_t)(P.T_in - 1) * BH;
  ushort_t* pAh = P.h0Ahi;
  ushort_t* pAl = P.h0Alo;
  #pragma unroll 1
  for (int t = 0; t < P.n_pred; ++t) {
    const int n0 = p0 ^ 1;
    if (t == 0) {
      phase_mm<1, 3, 2, 0, false, 256>(smem, tid, dMb, djb, true,
          P.ctxh + (size_t)(P.T_in - 1) * LATENT, P.ctxl + (size_t)(P.T_in - 1) * LATENT,
          P.ctx_pitch, LATENT,
          P.wih0h, nullptr,
          d0ph, d0pl, H, H, P.whh0h,
          P.bih0, P.bhh0, h0f[p0], h0f[n0], h0hi[n0], h0lo[n0], H, nullptr, nullptr);
    } else {
      phase_mm<1, 3, 2, 0, false, 256>(smem, tid, dMb, djb, true,
          pAh + (size_t)(t - 1) * BH, pAl + (size_t)(t - 1) * BH, H, H,
          P.wfh, nullptr,
          d0ph, d0pl, H, H, P.whh0h,
          P.bf0, P.bhh0, h0f[p0], h0f[n0], h0hi[n0], h0lo[n0], H, nullptr, nullptr);
    }
    grid_barrier(P.bar, tid, bid);
    d0ph = h0hi[n0]; d0pl = h0lo[n0];
    const int n1 = p1 ^ 1;
    phase_mm<1, 3, 2, 0, false, 256>(smem, tid, dMb, djb, true,
        h0hi[n0], h0lo[n0], H, H,
        P.wih1h, nullptr,
        h1hi[p1], h1lo[p1], H, H, P.whh1h,
        P.bih1, P.bhh1, h1f[p1], h1f[n1], h1hi[n1], h1lo[n1], H, nullptr, nullptr);
    grid_barrier(P.bar, tid, bid);
    phase_mm<1, 1, 1, 1, false, 256>(smem, tid, dMb, djb, true,
        h1hi[n1], h1lo[n1], H, H,
        P.w1h, nullptr,
        nullptr, nullptr, 0, 0, nullptr,
        nullptr, nullptr, nullptr, nullptr,
        pAh + (size_t)t * BH, pAl + (size_t)t * BH, H, P.bp1, nullptr);
    grid_barrier(P.bar, tid, bid);
    p0 = n0; p1 = n1;
  }
}

// ---------------- final ys GEMM (parallel, CHUNKW=128) ----------------
__global__ __launch_bounds__(256, 2) void proj_out_kernel(
    const ushort_t* __restrict__ pAh, const ushort_t* __restrict__ pAl,
    const ushort_t* __restrict__ w2h, const float* __restrict__ bp2,
    float* __restrict__ out, int n_pred)
{
  __shared__ char smem[49152];
  const int tid = threadIdx.x;
  const int rt = blockIdx.x >> 4;
  const int ct = blockIdx.x & 15;
  phase_mm<2, 1, 1, 3, false, 128>(smem, tid, rt, ct, true,
      pAh, pAl, H, H,
      w2h, nullptr,
      nullptr, nullptr, 0, 0, nullptr,
      nullptr, nullptr, nullptr, nullptr,
      nullptr, nullptr, n_pred, bp2, out);
}

// ---------------- fp32 fallback (round-1, known-good) ----------------

__global__ __launch_bounds__(256) void gru_cell_kernel(
    const float* __restrict__ x, int xs, int Kih,
    const float* __restrict__ h_prev,
    const float* __restrict__ wih, const float* __restrict__ whh,
    const float* __restrict__ bih, const float* __restrict__ bhh,
    float* __restrict__ h_out)
{
  __shared__ float Xs[32][33];
  __shared__ float Ws[48][33];
  const int tid = threadIdx.x;
  const int b0 = blockIdx.x * 32;
  const int j0 = blockIdx.y * 16;
  const int bg = tid & 15;
  const int jj = tid >> 4;
  const int j = j0 + jj;
  float accA[2][3];
  float accB[2][3];
  #pragma unroll
  for (int g = 0; g < 3; ++g) {
    const float bi = bih[g * H + j];
    const float bh = bhh[g * H + j];
    accA[0][g] = bi; accA[1][g] = bi;
    accB[0][g] = bh; accB[1][g] = bh;
  }
  for (int k0 = 0; k0 < Kih; k0 += 32) {
    {
      const int rr = tid >> 3, c4 = (tid & 7) << 2;
      const float4 v = *reinterpret_cast<const float4*>(&x[(size_t)(b0 + rr) * xs + k0 + c4]);
      Xs[rr][c4 + 0] = v.x; Xs[rr][c4 + 1] = v.y; Xs[rr][c4 + 2] = v.z; Xs[rr][c4 + 3] = v.w;
    }
    for (int li = tid; li < 48 * 8; li += 256) {
      const int rr = li >> 3, c4 = (li & 7) << 2;
      const int g = rr >> 4, jr = rr & 15;
      const float4 v = *reinterpret_cast<const float4*>(&wih[(size_t)(g * H + j0 + jr) * Kih + k0 + c4]);
      Ws[rr][c4 + 0] = v.x; Ws[rr][c4 + 1] = v.y; Ws[rr][c4 + 2] = v.z; Ws[rr][c4 + 3] = v.w;
    }
    __syncthreads();
    #pragma unroll
    for (int k = 0; k < 32; ++k) {
      const float x0 = Xs[bg][k];
      const float x1 = Xs[bg + 16][k];
      #pragma unroll
      for (int g = 0; g < 3; ++g) {
        const float wv = Ws[g * 16 + jj][k];
        accA[0][g] = fmaf(x0, wv, accA[0][g]);
        accA[1][g] = fmaf(x1, wv, accA[1][g]);
      }
    }
    __syncthreads();
  }
  for (int k0 = 0; k0 < H; k0 += 32) {
    {
      const int rr = tid >> 3, c4 = (tid & 7) << 2;
      const float4 v = *reinterpret_cast<const float4*>(&h_prev[(size_t)(b0 + rr) * H + k0 + c4]);
      Xs[rr][c4 + 0] = v.x; Xs[rr][c4 + 1] = v.y; Xs[rr][c4 + 2] = v.z; Xs[rr][c4 + 3] = v.w;
    }
    for (int li = tid; li < 48 * 8; li += 256) {
      const int rr = li >> 3, c4 = (li & 7) << 2;
      const int g = rr >> 4, jr = rr & 15;
      const float4 v = *reinterpret_cast<const float4*>(&whh[(size_t)(g * H + j0 + jr) * H + k0 + c4]);
      Ws[rr][c4 + 0] = v.x; Ws[rr][c4 + 1] = v.y; Ws[rr][c4 + 2] = v.z; Ws[rr][c4 + 3] = v.w;
    }
    __syncthreads();
    #pragma unroll
    for (int k = 0; k < 32; ++k) {
      const float h0v = Xs[bg][k];
      const float h1v = Xs[bg + 16][k];
      #pragma unroll
      for (int g = 0; g < 3; ++g) {
        const float wv = Ws[g * 16 + jj][k];
        accB[0][g] = fmaf(h0v, wv, accB[0][g]);
        accB[1][g] = fmaf(h1v, wv, accB[1][g]);
      }
    }
    __syncthreads();
  }
  #pragma unroll
  for (int i = 0; i < 2; ++i) {
    const int b = b0 + bg + i * 16;
    const float hp = h_prev[(size_t)b * H + j];
    const float r = sigmoidf_(accA[i][0] + accB[i][0]);
    const float z = sigmoidf_(accA[i][1] + accB[i][1]);
    const float n = tanhf(accA[i][2] + r * accB[i][2]);
    h_out[(size_t)b * H + j] = (1.0f - z) * n + z * hp;
  }
}

__global__ __launch_bounds__(256) void gemm_bias_kernel(
    const float* __restrict__ X, int xs, int K,
    const float* __restrict__ W, const float* __restrict__ bias,
    float* __restrict__ out1, int o1s,
    float* __restrict__ out2, int o2s,
    int relu)
{
  __shared__ float Xs[32][33];
  __shared__ float Ws[16][33];
  const int tid = threadIdx.x;
  const int b0 = blockIdx.x * 32;
  const int n0 = blockIdx.y * 16;
  const int bg = tid & 15;
  const int nn = tid >> 4;
  const int n = n0 + nn;
  float acc0 = bias[n];
  float acc1 = acc0;
  for (int k0 = 0; k0 < K; k0 += 32) {
    {
      const int rr = tid >> 3, c4 = (tid & 7) << 2;
      const float4 v = *reinterpret_cast<const float4*>(&X[(size_t)(b0 + rr) * xs + k0 + c4]);
      Xs[rr][c4 + 0] = v.x; Xs[rr][c4 + 1] = v.y; Xs[rr][c4 + 2] = v.z; Xs[rr][c4 + 3] = v.w;
    }
    if (tid < 128) {
      const int rr = tid >> 3, c4 = (tid & 7) << 2;
      const float4 v = *reinterpret_cast<const float4*>(&W[(size_t)(n0 + rr) * K + k0 + c4]);
      Ws[rr][c4 + 0] = v.x; Ws[rr][c4 + 1] = v.y; Ws[rr][c4 + 2] = v.z; Ws[rr][c4 + 3] = v.w;
    }
    __syncthreads();
    #pragma unroll
    for (int k = 0; k < 32; ++k) {
      const float wv = Ws[nn][k];
      acc0 = fmaf(Xs[bg][k], wv, acc0);
      acc1 = fmaf(Xs[bg + 16][k], wv, acc1);
    }
    __syncthreads();
  }
  if (relu) { acc0 = fmaxf(acc0, 0.0f); acc1 = fmaxf(acc1, 0.0f); }
  const int ba = b0 + bg, bb = b0 + bg + 16;
  out1[(size_t)ba * o1s + n] = acc0;
  out1[(size_t)bb * o1s + n] = acc1;
  if (out2 != nullptr) {
    out2[(size_t)ba * o2s + n] = acc0;
    out2[(size_t)bb * o2s + n] = acc1;
  }
}

// ---------------- host launch ----------------

extern "C" void kernel_launch(void* const* d_in, const int* in_sizes, int n_in,
                              void* d_out, int out_size, void* d_ws, size_t ws_size,
                              hipStream_t stream) {
  (void)n_in;
  const float* ctx  = (const float*)d_in[0];
  const float* wih0 = (const float*)d_in[1];
  const float* whh0 = (const float*)d_in[2];
  const float* bih0 = (const float*)d_in[3];
  const float* bhh0 = (const float*)d_in[4];
  const float* wih1 = (const float*)d_in[5];
  const float* whh1 = (const float*)d_in[6];
  const float* bih1 = (const float*)d_in[7];
  const float* bhh1 = (const float*)d_in[8];
  const float* w1   = (const float*)d_in[9];
  const float* bp1  = (const float*)d_in[10];
  const float* w2   = (const float*)d_in[11];
  const float* bp2  = (const float*)d_in[12];

  const int T_in   = in_sizes[0] / (B * LATENT);
  const int n_pred = out_size / (B * LATENT);
  float* out = (float*)d_out;

  // ---- ws layout ----
  size_t cur = 0;
  auto alloc = [&](size_t bytes) -> void* {
    void* p = (char*)d_ws + cur;
    cur += (bytes + 255) & ~(size_t)255;
    return p;
  };
  const int E_wih0 = 3 * H * LATENT, E_whh0 = 3 * H * H;
  const int E_wih1 = 3 * H * H, E_whh1 = 3 * H * H;
  const int E_w1 = H * H, E_w2 = LATENT * H;
  const int E_wf = 3 * H * H;
  const int E_ctx = in_sizes[0];

  ushort_t* wih0h = (ushort_t*)alloc(E_wih0 * 2);
  ushort_t* whh0h = (ushort_t*)alloc(E_whh0 * 2);
  ushort_t* wih1h = (ushort_t*)alloc(E_wih1 * 2);
  ushort_t* whh1h = (ushort_t*)alloc(E_whh1 * 2);
  ushort_t* w1h   = (ushort_t*)alloc(E_w1 * 2);
  ushort_t* w2h   = (ushort_t*)alloc(E_w2 * 2);
  ushort_t* wfh   = (ushort_t*)alloc((size_t)E_wf * 2);
  ushort_t* ctxh  = (ushort_t*)alloc((size_t)E_ctx * 2);
  ushort_t* ctxl  = (ushort_t*)alloc((size_t)E_ctx * 2);
  ushort_t* h0Ahi = (ushort_t*)alloc((size_t)T_in * BH * 2);
  ushort_t* h0Alo = (ushort_t*)alloc((size_t)T_in * BH * 2);
  float* bf0 = (float*)alloc(3 * H * 4);
  size_t zero_start = cur;
  float* h0f[2]; float* h1f[2];
  ushort_t* h0hi[2]; ushort_t* h0lo[2]; ushort_t* h1hi[2]; ushort_t* h1lo[2];
  h0f[0] = (float*)alloc(BH * 4); h0f[1] = (float*)alloc(BH * 4);
  h1f[0] = (float*)alloc(BH * 4); h1f[1] = (float*)alloc(BH * 4);
  h0hi[0] = (ushort_t*)alloc(BH * 2); h0lo[0] = (ushort_t*)alloc(BH * 2);
  h0hi[1] = (ushort_t*)alloc(BH * 2); h0lo[1] = (ushort_t*)alloc(BH * 2);
  h1hi[0] = (ushort_t*)alloc(BH * 2); h1lo[0] = (ushort_t*)alloc(BH * 2);
  h1hi[1] = (ushort_t*)alloc(BH * 2); h1lo[1] = (ushort_t*)alloc(BH * 2);
  unsigned* bar = (unsigned*)alloc(16384);
  size_t zero_bytes = cur - zero_start;
  size_t required = cur;

  if (ws_size >= required && n_pred <= T_in) {
    auto splitA = [&](const float* s, ushort_t* hi, ushort_t* lo, int n) {
      int blocks = (n + 255) / 256; if (blocks > 2048) blocks = 2048;
      split_kernel<<<blocks, 256, 0, stream>>>(s, hi, lo, n);
    };
    auto splitW = [&](const float* s, ushort_t* hi, int n) {
      int blocks = (n + 255) / 256; if (blocks > 2048) blocks = 2048;
      split_hi_kernel<<<blocks, 256, 0, stream>>>(s, hi, n);
    };
    splitW(wih0, wih0h, E_wih0);
    splitW(whh0, whh0h, E_whh0);
    splitW(wih1, wih1h, E_wih1);
    splitW(whh1, whh1h, E_whh1);
    splitW(w1, w1h, E_w1);
    splitW(w2, w2h, E_w2);
    wf_kernel<<<dim3(3 * H / 32, H / 32), 256, 0, stream>>>(wih0, w2, wfh);
    bias_fuse_kernel<<<(3 * H + 255) / 256, 256, 0, stream>>>(wih0, bp2, bih0, bf0);
    splitA(ctx, ctxh, ctxl, E_ctx);
    {
      int n4 = (int)(zero_bytes / 16);
      zero4_kernel<<<2048, 256, 0, stream>>>((float4*)((char*)d_ws + zero_start), n4);
    }

    PParams P;
    P.ctxh = ctxh; P.ctxl = ctxl;
    P.wih0h = wih0h; P.whh0h = whh0h;
    P.wih1h = wih1h; P.whh1h = whh1h;
    P.w1h = w1h; P.wfh = wfh;
    P.bih0 = bih0; P.bhh0 = bhh0; P.bih1 = bih1; P.bhh1 = bhh1; P.bp1 = bp1;
    P.bf0 = bf0;
    P.h0f0 = h0f[0]; P.h0f1 = h0f[1]; P.h1f0 = h1f[0]; P.h1f1 = h1f[1];
    P.h0hi0 = h0hi[0]; P.h0lo0 = h0lo[0]; P.h0hi1 = h0hi[1]; P.h0lo1 = h0lo[1];
    P.h1hi0 = h1hi[0]; P.h1lo0 = h1lo[0]; P.h1hi1 = h1hi[1]; P.h1lo1 = h1lo[1];
    P.h0Ahi = h0Ahi; P.h0Alo = h0Alo;
    P.bar = bar;
    P.T_in = T_in; P.n_pred = n_pred; P.ctx_pitch = T_in * LATENT;

    gru_persistent<<<256, 256, 0, stream>>>(P);

    const int rowtiles = (n_pred * B) / 32;
    proj_out_kernel<<<rowtiles * 16, 256, 0, stream>>>(h0Ahi, h0Alo, w2h, bp2, out, n_pred);
    return;
  }

  // ---------- fp32 fallback path (round-1) ----------
  float* ws = (float*)d_ws;
  float* h0a = ws;
  float* h0b = h0a + (size_t)BH;
  float* h1a = h0b + (size_t)BH;
  float* h1b = h1a + (size_t)BH;
  float* p   = h1b + (size_t)BH;
  {
    int n4 = (4 * BH) / 4;
    zero4_kernel<<<256, 256, 0, stream>>>((float4*)h0a, n4);
  }
  float* y = p + (size_t)BH;
  float* h0p = h0a; float* h0n = h0b;
  float* h1p = h1a; float* h1n = h1b;
  const dim3 cgrid(4, 64);
  for (int t = 0; t < T_in; ++t) {
    const float* x = ctx + (size_t)t * LATENT;
    gru_cell_kernel<<<cgrid, 256, 0, stream>>>(x, T_in * LATENT, LATENT,
                                               h0p, wih0, whh0, bih0, bhh0, h0n);
    gru_cell_kernel<<<cgrid, 256, 0, stream>>>(h0n, H, H,
                                               h1p, wih1, whh1, bih1, bhh1, h1n);
    float* tmp;
    tmp = h0p; h0p = h0n; h0n = tmp;
    tmp = h1p; h1p = h1n; h1n = tmp;
  }
  for (int t = 0; t < n_pred; ++t) {
    const float* x; int xstride;
    if (t == 0) { x = ctx + (size_t)(T_in - 1) * LATENT; xstride = T_in * LATENT; }
    else        { x = y; xstride = LATENT; }
    gru_cell_kernel<<<cgrid, 256, 0, stream>>>(x, xstride, LATENT,
                                               h0p, wih0, whh0, bih0, bhh0, h0n);
    gru_cell_kernel<<<cgrid, 256, 0, stream>>>(h0n, H, H,
                                               h1p, wih1, whh1, bih1, bhh1, h1n);
    gemm_bias_kernel<<<dim3(4, H / 16), 256, 0, stream>>>(h1n, H, H, w1, bp1,
                                                          p, H, nullptr, 0, 1);
    gemm_bias_kernel<<<dim3(4, LATENT / 16), 256, 0, stream>>>(p, H, H, w2, bp2,
                                                               y, LATENT,
                                                               out + (size_t)t * LATENT,
                                                               n_pred * LATENT, 0);
    float* tmp;
    tmp = h0p; h0p = h0n; h0n = tmp;
    tmp = h1p; h1p = h1n; h1n = tmp;
  }
}

// Round 17
// 6466.491 us; speedup vs baseline: 1.0716x; 1.0716x over previous
//
#include <hip/hip_runtime.h>
#include <math.h>

#define B 128
#define LATENT 512
#define H 1024
#define BH (B * H)

typedef unsigned short ushort_t;
typedef unsigned int uint_t;
typedef __bf16 bf16x8 __attribute__((ext_vector_type(8)));
typedef float f32x4 __attribute__((ext_vector_type(4)));

#define AT_LD(p)    __hip_atomic_load((p), __ATOMIC_RELAXED, __HIP_MEMORY_SCOPE_AGENT)
#define AT_ST(p, v) __hip_atomic_store((p), (v), __ATOMIC_RELAXED, __HIP_MEMORY_SCOPE_AGENT)

// ---------------- common small kernels ----------------

__global__ __launch_bounds__(256) void zero4_kernel(float4* __restrict__ p, int n4) {
  int i = blockIdx.x * blockDim.x + threadIdx.x;
  int stride = gridDim.x * blockDim.x;
  float4 z = {0.f, 0.f, 0.f, 0.f};
  for (; i < n4; i += stride) p[i] = z;
}

__device__ __forceinline__ void split_bf16(float f, ushort_t& h, ushort_t& l) {
  uint_t u = __float_as_uint(f);
  uint_t hb = (u + 0x7FFFu + ((u >> 16) & 1u)) >> 16;
  float fh = __uint_as_float(hb << 16);
  float r = f - fh;
  uint_t v = __float_as_uint(r);
  uint_t lb = (v + 0x7FFFu + ((v >> 16) & 1u)) >> 16;
  h = (ushort_t)hb; l = (ushort_t)lb;
}

__global__ __launch_bounds__(256) void split_kernel(const float* __restrict__ src,
                                                    ushort_t* __restrict__ hi,
                                                    ushort_t* __restrict__ lo, int n) {
  int i = blockIdx.x * blockDim.x + threadIdx.x;
  int stride = gridDim.x * blockDim.x;
  for (; i < n; i += stride) {
    ushort_t h, l;
    split_bf16(src[i], h, l);
    hi[i] = h; lo[i] = l;
  }
}

__global__ __launch_bounds__(256) void split_hi_kernel(const float* __restrict__ src,
                                                       ushort_t* __restrict__ hi, int n) {
  int i = blockIdx.x * blockDim.x + threadIdx.x;
  int stride = gridDim.x * blockDim.x;
  for (; i < n; i += stride) {
    uint_t u = __float_as_uint(src[i]);
    hi[i] = (ushort_t)((u + 0x7FFFu + ((u >> 16) & 1u)) >> 16);
  }
}

// wf = wih0 @ w2  (fp32 GEMM, hi split)
__global__ __launch_bounds__(256) void wf_kernel(const float* __restrict__ wih0,
                                                 const float* __restrict__ w2,
                                                 ushort_t* __restrict__ wfh) {
  __shared__ float As[32][33];
  __shared__ float Bs[32][33];
  const int i0 = blockIdx.x * 32;
  const int k0 = blockIdx.y * 32;
  const int tid = threadIdx.x;
  const int r = tid >> 3, c4 = (tid & 7) << 2;
  float acc[4] = {0.f, 0.f, 0.f, 0.f};
  for (int m0 = 0; m0 < LATENT; m0 += 32) {
    {
      const float4 v = *reinterpret_cast<const float4*>(&wih0[(size_t)(i0 + r) * LATENT + m0 + c4]);
      As[r][c4] = v.x; As[r][c4 + 1] = v.y; As[r][c4 + 2] = v.z; As[r][c4 + 3] = v.w;
      const float4 w = *reinterpret_cast<const float4*>(&w2[(size_t)(m0 + r) * H + k0 + c4]);
      Bs[r][c4] = w.x; Bs[r][c4 + 1] = w.y; Bs[r][c4 + 2] = w.z; Bs[r][c4 + 3] = w.w;
    }
    __syncthreads();
    #pragma unroll
    for (int mm = 0; mm < 32; ++mm) {
      const float a = As[r][mm];
      #pragma unroll
      for (int x = 0; x < 4; ++x) acc[x] = fmaf(a, Bs[mm][c4 + x], acc[x]);
    }
    __syncthreads();
  }
  #pragma unroll
  for (int x = 0; x < 4; ++x) {
    uint_t u = __float_as_uint(acc[x]);
    wfh[(size_t)(i0 + r) * H + k0 + c4 + x] =
        (ushort_t)((u + 0x7FFFu + ((u >> 16) & 1u)) >> 16);
  }
}

// bf0[g] = bih0[g] + dot(wih0[g,:], bp2)
__global__ __launch_bounds__(256) void bias_fuse_kernel(const float* __restrict__ wih0,
                                                        const float* __restrict__ bp2,
                                                        const float* __restrict__ bih0,
                                                        float* __restrict__ bf0) {
  int g = blockIdx.x * blockDim.x + threadIdx.x;
  if (g < 3 * H) {
    float s = bih0[g];
    const float* row = wih0 + (size_t)g * LATENT;
    #pragma unroll 4
    for (int l = 0; l < LATENT; ++l) s = fmaf(row[l], bp2[l], s);
    bf0[g] = s;
  }
}

__device__ __forceinline__ float sigmoidf_(float v) { return 1.0f / (1.0f + expf(-v)); }

// ---------------- RELAXED grid barrier (r16, correct) ----------------
__device__ __forceinline__ void grid_barrier(unsigned* bar, int tid, int bid) {
  __syncthreads();
  if (tid == 0) {
    const int g = bid & 7;
    unsigned* arr    = bar + (g << 6);
    unsigned* rel    = bar + 1024 + (g << 6);
    unsigned* master = bar + 2048;
    unsigned gen = AT_LD(rel);
    unsigned a = __hip_atomic_fetch_add(arr, 1u, __ATOMIC_RELAXED, __HIP_MEMORY_SCOPE_AGENT);
    if (a == 31u) {
      AT_ST(arr, 0u);
      unsigned m = __hip_atomic_fetch_add(master, 1u, __ATOMIC_RELAXED, __HIP_MEMORY_SCOPE_AGENT);
      if (m == 7u) {
        AT_ST(master, 0u);
        #pragma unroll
        for (int i = 0; i < 8; ++i)
          __hip_atomic_fetch_add(bar + 1024 + (i << 6), 1u, __ATOMIC_RELAXED, __HIP_MEMORY_SCOPE_AGENT);
      }
    }
    while (AT_LD(rel) == gen)
      __builtin_amdgcn_s_sleep(1);
  }
  __syncthreads();
}

// ---------------- one GEMM phase (r16 body: cached W staging, atomic A state) ----------------
template <int NJ, int NG, int PH, int EPI, bool WLO, int CHUNKW>
__device__ __forceinline__ void phase_mm(
    char* smem, const int tid, const int Mb, const int jb, const bool active,
    const ushort_t* aAh, const ushort_t* aAl, int aApitch, int K1,
    const ushort_t* wAh, const ushort_t* wAl,
    const ushort_t* aBh, const ushort_t* aBl, int aBpitch, int K2,
    const ushort_t* wBh,
    const float* bih, const float* bhh,
    const float* h_prev, float* h_out,
    ushort_t* out_hi, ushort_t* out_lo, int split_pitch,
    const float* bias, float* out_f32)
{
  if (!active) return;
  constexpr int KST = CHUNKW / 128;
  constexpr int SLOTB = CHUNKW * 32;
  constexpr int NW = NJ * NG;
  constexpr int NSLOTA = 4 + NW * (WLO ? 2 : 1);
  constexpr int NSLOTB = 4 + NW;
  constexpr int BUFB = NSLOTA * SLOTB;
  constexpr int NPG = PH * NW;
  constexpr int CW = NJ * 16;
  constexpr int CSHIFT = (CHUNKW == 256) ? 8 : 7;

  const int b0 = Mb * 32;
  const int j0 = jb * CW;
  const int NC1 = K1 >> CSHIFT;
  const int NC2 = (PH == 2) ? (K2 >> CSHIFT) : 0;
  const int NC = NC1 + NC2;

  const char* g[NSLOTA];
  auto build = [&](const ushort_t* ah, const ushort_t* al, int apitch,
                   const ushort_t* wh, const ushort_t* wl, int K) {
    const int rowt = tid >> 4;
    const int cp = tid & 15;
    const int cc = cp ^ rowt;
    #pragma unroll
    for (int u = 0; u < NSLOTA; ++u) {
      const ushort_t* basep; size_t off;
      if (u < 2)      { basep = ah; off = (size_t)(b0 + u * 16 + rowt) * apitch + cc * 8; }
      else if (u < 4) { basep = al; off = (size_t)(b0 + (u - 2) * 16 + rowt) * apitch + cc * 8; }
      else if (u < 4 + NW) {
        const int w = u - 4, jt = w % NJ, gate = w / NJ;
        const int wrow = (NG == 3) ? (gate * H + j0 + jt * 16 + rowt) : (j0 + jt * 16 + rowt);
        basep = wh; off = (size_t)wrow * K + cc * 8;
      } else {
        const int w = u - 4 - NW, jt = w % NJ, gate = w / NJ;
        const int wrow = (NG == 3) ? (gate * H + j0 + jt * 16 + rowt) : (j0 + jt * 16 + rowt);
        basep = (wl != nullptr) ? wl : wh; off = (size_t)wrow * K + cc * 8;
      }
      g[u] = (const char*)(basep + off);
    }
  };

  const int s = tid >> 6;
  const int q = (tid >> 4) & 3;
  const int r = tid & 15;
  int gsv[KST];
  #pragma unroll
  for (int k2 = 0; k2 < KST; ++k2) {
    const int G = s * (4 * KST) + k2 * 4 + q;
    gsv[k2] = (G >> 4) * 4096 + ((G & 15) ^ r) * 16;
  }
  const int rbase = r * 256;

  f32x4 accA[NJ][NG][2];
  f32x4 accB[NJ][NG][2];
  #pragma unroll
  for (int jt = 0; jt < NJ; ++jt)
    #pragma unroll
    for (int gg = 0; gg < NG; ++gg)
      #pragma unroll
      for (int mf = 0; mf < 2; ++mf) {
        accA[jt][gg][mf] = (f32x4){0.f, 0.f, 0.f, 0.f};
        accB[jt][gg][mf] = (f32x4){0.f, 0.f, 0.f, 0.f};
      }

  const unsigned wofs = (unsigned)(tid >> 6) * 1024;
  auto issueW = [&](int bsel, int koff, int nslot) {
    #pragma unroll
    for (int u = 4; u < NSLOTA; ++u) {
      if (u < nslot) {
        #pragma unroll
        for (int j = 0; j < KST; ++j) {
          __builtin_amdgcn_global_load_lds(
              (const __attribute__((address_space(1))) void*)(g[u] + koff + j * 256),
              (__attribute__((address_space(3))) void*)(smem + bsel * BUFB + u * SLOTB + j * 4096 + wofs),
              16, 0, 0);
        }
      }
    }
  };

  uint4 aReg[4][KST];
  auto loadA = [&](int koff) {
    #pragma unroll
    for (int u = 0; u < 4; ++u)
      #pragma unroll
      for (int j = 0; j < KST; ++j) {
        uint_t* p = (uint_t*)(void*)(g[u] + koff + j * 256);
        aReg[u][j].x = AT_LD(p + 0);
        aReg[u][j].y = AT_LD(p + 1);
        aReg[u][j].z = AT_LD(p + 2);
        aReg[u][j].w = AT_LD(p + 3);
      }
  };
  auto writeA = [&](int bsel) {
    #pragma unroll
    for (int u = 0; u < 4; ++u)
      #pragma unroll
      for (int j = 0; j < KST; ++j)
        *(uint4*)(smem + bsel * BUFB + u * SLOTB + j * 4096 + tid * 16) = aReg[u][j];
  };

  auto computeA = [&](int bsel) {
    const char* base = smem + bsel * BUFB;
    #pragma unroll
    for (int k2 = 0; k2 < KST; ++k2) {
      const int fo = rbase + gsv[k2];
      bf16x8 ah0 = *(const bf16x8*)(base + 0 * SLOTB + fo);
      bf16x8 ah1 = *(const bf16x8*)(base + 1 * SLOTB + fo);
      bf16x8 al0 = *(const bf16x8*)(base + 2 * SLOTB + fo);
      bf16x8 al1 = *(const bf16x8*)(base + 3 * SLOTB + fo);
      #pragma unroll
      for (int gg = 0; gg < NG; ++gg)
        #pragma unroll
        for (int jt = 0; jt < NJ; ++jt) {
          const int w = gg * NJ + jt;
          bf16x8 wh = *(const bf16x8*)(base + (4 + w) * SLOTB + fo);
          accA[jt][gg][0] = __builtin_amdgcn_mfma_f32_16x16x32_bf16(ah0, wh, accA[jt][gg][0], 0, 0, 0);
          if (WLO) {
            bf16x8 wl = *(const bf16x8*)(base + (4 + NW + w) * SLOTB + fo);
            accA[jt][gg][0] = __builtin_amdgcn_mfma_f32_16x16x32_bf16(ah0, wl, accA[jt][gg][0], 0, 0, 0);
            accA[jt][gg][1] = __builtin_amdgcn_mfma_f32_16x16x32_bf16(ah1, wl, accA[jt][gg][1], 0, 0, 0);
          }
          accA[jt][gg][0] = __builtin_amdgcn_mfma_f32_16x16x32_bf16(al0, wh, accA[jt][gg][0], 0, 0, 0);
          accA[jt][gg][1] = __builtin_amdgcn_mfma_f32_16x16x32_bf16(ah1, wh, accA[jt][gg][1], 0, 0, 0);
          accA[jt][gg][1] = __builtin_amdgcn_mfma_f32_16x16x32_bf16(al1, wh, accA[jt][gg][1], 0, 0, 0);
        }
    }
  };
  auto computeB = [&](int bsel) {
    const char* base = smem + bsel * BUFB;
    #pragma unroll
    for (int k2 = 0; k2 < KST; ++k2) {
      const int fo = rbase + gsv[k2];
      bf16x8 ah0 = *(const bf16x8*)(base + 0 * SLOTB + fo);
      bf16x8 ah1 = *(const bf16x8*)(base + 1 * SLOTB + fo);
      bf16x8 al0 = *(const bf16x8*)(base + 2 * SLOTB + fo);
      bf16x8 al1 = *(const bf16x8*)(base + 3 * SLOTB + fo);
      #pragma unroll
      for (int gg = 0; gg < NG; ++gg)
        #pragma unroll
        for (int jt = 0; jt < NJ; ++jt) {
          const int w = gg * NJ + jt;
          bf16x8 wh = *(const bf16x8*)(base + (4 + w) * SLOTB + fo);
          accB[jt][gg][0] = __builtin_amdgcn_mfma_f32_16x16x32_bf16(ah0, wh, accB[jt][gg][0], 0, 0, 0);
          accB[jt][gg][0] = __builtin_amdgcn_mfma_f32_16x16x32_bf16(al0, wh, accB[jt][gg][0], 0, 0, 0);
          accB[jt][gg][1] = __builtin_amdgcn_mfma_f32_16x16x32_bf16(ah1, wh, accB[jt][gg][1], 0, 0, 0);
          accB[jt][gg][1] = __builtin_amdgcn_mfma_f32_16x16x32_bf16(al1, wh, accB[jt][gg][1], 0, 0, 0);
        }
    }
  };

  // prologue: chunk 0 fully staged
  build(aAh, aAl, aApitch, wAh, wAl, K1);
  issueW(0, 0, NSLOTA);
  loadA(0);
  writeA(0);

  #pragma unroll 1
  for (int c = 0; c < NC; ++c) {
    __syncthreads();
    if (c + 1 < NC) {
      if (PH == 2 && c + 1 == NC1) {
        build(aBh, aBl, aBpitch, wBh, nullptr, K2);
        issueW((c + 1) & 1, 0, NSLOTB);
        loadA(0);
      } else {
        const bool isB = (PH == 2) && (c + 1 >= NC1);
        const int koff = (isB ? (c + 1 - NC1) : (c + 1)) * (CHUNKW * 2);
        issueW((c + 1) & 1, koff, isB ? NSLOTB : NSLOTA);
        loadA(koff);
      }
    }
    if (PH == 1 || c < NC1) computeA(c & 1);
    else                    computeB(c & 1);
    if (c + 1 < NC) writeA((c + 1) & 1);
  }
  __syncthreads();

  // ---- cross-wave reduce (alias smem) ----
  const int lane = tid & 63;
  #pragma unroll
  for (int gg = 0; gg < NG; ++gg)
    #pragma unroll
    for (int jt = 0; jt < NJ; ++jt)
      #pragma unroll
      for (int mf = 0; mf < 2; ++mf) {
        const int w = gg * NJ + jt;
        *(f32x4*)(smem + (size_t)(((s * NPG + w) * 2 + mf) * 64 + lane) * 16) = accA[jt][gg][mf];
        if (PH == 2)
          *(f32x4*)(smem + (size_t)(((s * NPG + NW + w) * 2 + mf) * 64 + lane) * 16) = accB[jt][gg][mf];
      }
  __syncthreads();

  for (int o = tid; o < 32 * CW; o += 256) {
    const int row = o / CW, c = o % CW;
    const int jt = c >> 4, cr = c & 15;
    const int mf = row >> 4, br = row & 15, qq = br >> 2, rg = br & 3;
    const int ln = cr + qq * 16;
    float v[PH * NG];
    #pragma unroll
    for (int pg = 0; pg < PH * NG; ++pg) {
      const int w = (pg < NG) ? (pg * NJ + jt) : (NW + (pg - NG) * NJ + jt);
      float sum = 0.f;
      #pragma unroll
      for (int ss = 0; ss < 4; ++ss)
        sum += *(const float*)(smem + (size_t)(((ss * NPG + w) * 2 + mf) * 64 + ln) * 16 + rg * 4);
      v[pg] = sum;
    }
    const int bglob = b0 + row, jglob = j0 + c;
    if (EPI == 0) {
      float ir = v[0] + bih[jglob];
      float iz = v[1] + bih[H + jglob];
      float in_ = v[2] + bih[2 * H + jglob];
      float hr = v[3] + bhh[jglob];
      float hz = v[4] + bhh[H + jglob];
      float hn = v[5] + bhh[2 * H + jglob];
      float rr_ = sigmoidf_(ir + hr);
      float zz_ = sigmoidf_(iz + hz);
      float nn_ = tanhf(in_ + rr_ * hn);
      float hp = AT_LD((float*)&h_prev[(size_t)bglob * H + jglob]);
      float ho = (1.f - zz_) * nn_ + zz_ * hp;
      AT_ST(&h_out[(size_t)bglob * H + jglob], ho);
      ushort_t hb, lb;
      split_bf16(ho, hb, lb);
      AT_ST(&out_hi[(size_t)bglob * H + jglob], hb);
      AT_ST(&out_lo[(size_t)bglob * H + jglob], lb);
    } else if (EPI == 1) {
      float vv = v[0] + bias[jglob];
      vv = fmaxf(vv, 0.f);
      ushort_t hb, lb;
      split_bf16(vv, hb, lb);
      AT_ST(&out_hi[(size_t)bglob * split_pitch + jglob], hb);
      AT_ST(&out_lo[(size_t)bglob * split_pitch + jglob], lb);
    } else {
      float vv = v[0] + bias[jglob];
      const int tt = bglob >> 7, bb2 = bglob & 127;
      out_f32[((size_t)bb2 * split_pitch + tt) * LATENT + jglob] = vv;
    }
  }
  __syncthreads();
}

// ---------------- persistent kernel: XCD-clustered block mapping ----------------

struct PParams {
  const ushort_t *ctxh, *ctxl;
  const ushort_t *wih0h, *whh0h;
  const ushort_t *wih1h, *whh1h;
  const ushort_t *w1h;
  const ushort_t *wfh;
  const float *bih0, *bhh0, *bih1, *bhh1, *bp1;
  const float *bf0;
  float *h0f0, *h0f1, *h1f0, *h1f1;
  ushort_t *h0hi0, *h0lo0, *h0hi1, *h0lo1;
  ushort_t *h1hi0, *h1lo0, *h1hi1, *h1lo1;
  ushort_t *h0Ahi, *h0Alo;
  unsigned* bar;
  int T_in, n_pred, ctx_pitch;
};

__global__ __launch_bounds__(256, 1) void gru_persistent(PParams P) {
  __shared__ char smem[114688];
  const int tid = threadIdx.x;
  const int bid = blockIdx.x;

  float* h0f[2] = {P.h0f0, P.h0f1};
  float* h1f[2] = {P.h1f0, P.h1f1};
  ushort_t* h0hi[2] = {P.h0hi0, P.h0hi1};
  ushort_t* h0lo[2] = {P.h0lo0, P.h0lo1};
  ushort_t* h1hi[2] = {P.h1hi0, P.h1hi1};
  ushort_t* h1lo[2] = {P.h1lo0, P.h1lo1};

  int p0 = 0, p1 = 0;

  // -------- pipelined encoder (CHUNKW=128), XCD-clustered j-tiles --------
  // bid<128 -> L0, else L1. idx bits: [0:3]=XCD, [3:5]=jb-within-XCD, [5:7]=Mb.
  // XCD k owns cols [k*128, k*128+128): its W slice (~1.1-1.5MB) stays L2-resident.
  const int idx = (bid < 128) ? bid : (bid - 128);
  const int eMb = (idx >> 5) & 3;
  const int ejb = (idx & 7) * 4 + ((idx >> 3) & 3);
  #pragma unroll 1
  for (int p = 0; p <= P.T_in; ++p) {
    const int n0 = p0 ^ 1, n1 = p1 ^ 1;
    if (bid < 128) {
      if (p < P.T_in) {
        const int t = p;
        phase_mm<2, 3, 2, 0, false, 128>(smem, tid, eMb, ejb, true,
            P.ctxh + (size_t)t * LATENT, P.ctxl + (size_t)t * LATENT, P.ctx_pitch, LATENT,
            P.wih0h, nullptr,
            (t == 0) ? P.h0hi0 : P.h0Ahi + (size_t)(t - 1) * BH,
            (t == 0) ? P.h0lo0 : P.h0Alo + (size_t)(t - 1) * BH, H, H, P.whh0h,
            P.bih0, P.bhh0, h0f[p0], h0f[n0],
            P.h0Ahi + (size_t)t * BH, P.h0Alo + (size_t)t * BH, H, nullptr, nullptr);
      }
    } else {
      if (p >= 1) {
        const int t = p - 1;
        phase_mm<2, 3, 2, 0, false, 128>(smem, tid, eMb, ejb, true,
            P.h0Ahi + (size_t)t * BH, P.h0Alo + (size_t)t * BH, H, H,
            P.wih1h, nullptr,
            h1hi[p1], h1lo[p1], H, H, P.whh1h,
            P.bih1, P.bhh1, h1f[p1], h1f[n1],
            h1hi[n1], h1lo[n1], H, nullptr, nullptr);
      }
    }
    grid_barrier(P.bar, tid, bid);
    if (p < P.T_in) p0 = n0;
    if (p >= 1) p1 = n1;
  }

  // -------- decoder (CHUNKW=256), XCD-clustered: bid bits [0:3]=XCD,
  // [3:6]=jb-within-XCD (8), [6:8]=Mb (4). XCD k owns cols [k*128, k*128+128):
  // per-XCD W set (D0 wf+whh0 + D1 wih1+whh1 + DP w1 slices) ~3.3MB < 4MB L2.
  const int dMb = (bid >> 6) & 3;
  const int djb = (bid & 7) * 8 + ((bid >> 3) & 7);
  const ushort_t* d0ph = P.h0Ahi + (size_t)(P.T_in - 1) * BH;
  const ushort_t* d0pl = P.h0Alo + (size_t)(P.T_in - 1) * BH;
  ushort_t* pAh = P.h0Ahi;
  ushort_t* pAl = P.h0Alo;
  #pragma unroll 1
  for (int t = 0; t < P.n_pred; ++t) {
    const int n0 = p0 ^ 1;
    if (t == 0) {
      phase_mm<1, 3, 2, 0, false, 256>(smem, tid, dMb, djb, true,
          P.ctxh + (size_t)(P.T_in - 1) * LATENT, P.ctxl + (size_t)(P.T_in - 1) * LATENT,
          P.ctx_pitch, LATENT,
          P.wih0h, nullptr,
          d0ph, d0pl, H, H, P.whh0h,
          P.bih0, P.bhh0, h0f[p0], h0f[n0], h0hi[n0], h0lo[n0], H, nullptr, nullptr);
    } else {
      phase_mm<1, 3, 2, 0, false, 256>(smem, tid, dMb, djb, true,
          pAh + (size_t)(t - 1) * BH, pAl + (size_t)(t - 1) * BH, H, H,
          P.wfh, nullptr,
          d0ph, d0pl, H, H, P.whh0h,
          P.bf0, P.bhh0, h0f[p0], h0f[n0], h0hi[n0], h0lo[n0], H, nullptr, nullptr);
    }
    grid_barrier(P.bar, tid, bid);
    d0ph = h0hi[n0]; d0pl = h0lo[n0];
    const int n1 = p1 ^ 1;
    phase_mm<1, 3, 2, 0, false, 256>(smem, tid, dMb, djb, true,
        h0hi[n0], h0lo[n0], H, H,
        P.wih1h, nullptr,
        h1hi[p1], h1lo[p1], H, H, P.whh1h,
        P.bih1, P.bhh1, h1f[p1], h1f[n1], h1hi[n1], h1lo[n1], H, nullptr, nullptr);
    grid_barrier(P.bar, tid, bid);
    phase_mm<1, 1, 1, 1, false, 256>(smem, tid, dMb, djb, true,
        h1hi[n1], h1lo[n1], H, H,
        P.w1h, nullptr,
        nullptr, nullptr, 0, 0, nullptr,
        nullptr, nullptr, nullptr, nullptr,
        pAh + (size_t)t * BH, pAl + (size_t)t * BH, H, P.bp1, nullptr);
    grid_barrier(P.bar, tid, bid);
    p0 = n0; p1 = n1;
  }
}

// ---------------- final ys GEMM (parallel, CHUNKW=128) ----------------
__global__ __launch_bounds__(256, 2) void proj_out_kernel(
    const ushort_t* __restrict__ pAh, const ushort_t* __restrict__ pAl,
    const ushort_t* __restrict__ w2h, const float* __restrict__ bp2,
    float* __restrict__ out, int n_pred)
{
  __shared__ char smem[49152];
  const int tid = threadIdx.x;
  const int rt = blockIdx.x >> 4;
  const int ct = blockIdx.x & 15;
  phase_mm<2, 1, 1, 3, false, 128>(smem, tid, rt, ct, true,
      pAh, pAl, H, H,
      w2h, nullptr,
      nullptr, nullptr, 0, 0, nullptr,
      nullptr, nullptr, nullptr, nullptr,
      nullptr, nullptr, n_pred, bp2, out);
}

// ---------------- fp32 fallback (round-1, known-good) ----------------

__global__ __launch_bounds__(256) void gru_cell_kernel(
    const float* __restrict__ x, int xs, int Kih,
    const float* __restrict__ h_prev,
    const float* __restrict__ wih, const float* __restrict__ whh,
    const float* __restrict__ bih, const float* __restrict__ bhh,
    float* __restrict__ h_out)
{
  __shared__ float Xs[32][33];
  __shared__ float Ws[48][33];
  const int tid = threadIdx.x;
  const int b0 = blockIdx.x * 32;
  const int j0 = blockIdx.y * 16;
  const int bg = tid & 15;
  const int jj = tid >> 4;
  const int j = j0 + jj;
  float accA[2][3];
  float accB[2][3];
  #pragma unroll
  for (int g = 0; g < 3; ++g) {
    const float bi = bih[g * H + j];
    const float bh = bhh[g * H + j];
    accA[0][g] = bi; accA[1][g] = bi;
    accB[0][g] = bh; accB[1][g] = bh;
  }
  for (int k0 = 0; k0 < Kih; k0 += 32) {
    {
      const int rr = tid >> 3, c4 = (tid & 7) << 2;
      const float4 v = *reinterpret_cast<const float4*>(&x[(size_t)(b0 + rr) * xs + k0 + c4]);
      Xs[rr][c4 + 0] = v.x; Xs[rr][c4 + 1] = v.y; Xs[rr][c4 + 2] = v.z; Xs[rr][c4 + 3] = v.w;
    }
    for (int li = tid; li < 48 * 8; li += 256) {
      const int rr = li >> 3, c4 = (li & 7) << 2;
      const int g = rr >> 4, jr = rr & 15;
      const float4 v = *reinterpret_cast<const float4*>(&wih[(size_t)(g * H + j0 + jr) * Kih + k0 + c4]);
      Ws[rr][c4 + 0] = v.x; Ws[rr][c4 + 1] = v.y; Ws[rr][c4 + 2] = v.z; Ws[rr][c4 + 3] = v.w;
    }
    __syncthreads();
    #pragma unroll
    for (int k = 0; k < 32; ++k) {
      const float x0 = Xs[bg][k];
      const float x1 = Xs[bg + 16][k];
      #pragma unroll
      for (int g = 0; g < 3; ++g) {
        const float wv = Ws[g * 16 + jj][k];
        accA[0][g] = fmaf(x0, wv, accA[0][g]);
        accA[1][g] = fmaf(x1, wv, accA[1][g]);
      }
    }
    __syncthreads();
  }
  for (int k0 = 0; k0 < H; k0 += 32) {
    {
      const int rr = tid >> 3, c4 = (tid & 7) << 2;
      const float4 v = *reinterpret_cast<const float4*>(&h_prev[(size_t)(b0 + rr) * H + k0 + c4]);
      Xs[rr][c4 + 0] = v.x; Xs[rr][c4 + 1] = v.y; Xs[rr][c4 + 2] = v.z; Xs[rr][c4 + 3] = v.w;
    }
    for (int li = tid; li < 48 * 8; li += 256) {
      const int rr = li >> 3, c4 = (li & 7) << 2;
      const int g = rr >> 4, jr = rr & 15;
      const float4 v = *reinterpret_cast<const float4*>(&whh[(size_t)(g * H + j0 + jr) * H + k0 + c4]);
      Ws[rr][c4 + 0] = v.x; Ws[rr][c4 + 1] = v.y; Ws[rr][c4 + 2] = v.z; Ws[rr][c4 + 3] = v.w;
    }
    __syncthreads();
    #pragma unroll
    for (int k = 0; k < 32; ++k) {
      const float h0v = Xs[bg][k];
      const float h1v = Xs[bg + 16][k];
      #pragma unroll
      for (int g = 0; g < 3; ++g) {
        const float wv = Ws[g * 16 + jj][k];
        accB[0][g] = fmaf(h0v, wv, accB[0][g]);
        accB[1][g] = fmaf(h1v, wv, accB[1][g]);
      }
    }
    __syncthreads();
  }
  #pragma unroll
  for (int i = 0; i < 2; ++i) {
    const int b = b0 + bg + i * 16;
    const float hp = h_prev[(size_t)b * H + j];
    const float r = sigmoidf_(accA[i][0] + accB[i][0]);
    const float z = sigmoidf_(accA[i][1] + accB[i][1]);
    const float n = tanhf(accA[i][2] + r * accB[i][2]);
    h_out[(size_t)b * H + j] = (1.0f - z) * n + z * hp;
  }
}

__global__ __launch_bounds__(256) void gemm_bias_kernel(
    const float* __restrict__ X, int xs, int K,
    const float* __restrict__ W, const float* __restrict__ bias,
    float* __restrict__ out1, int o1s,
    float* __restrict__ out2, int o2s,
    int relu)
{
  __shared__ float Xs[32][33];
  __shared__ float Ws[16][33];
  const int tid = threadIdx.x;
  const int b0 = blockIdx.x * 32;
  const int n0 = blockIdx.y * 16;
  const int bg = tid & 15;
  const int nn = tid >> 4;
  const int n = n0 + nn;
  float acc0 = bias[n];
  float acc1 = acc0;
  for (int k0 = 0; k0 < K; k0 += 32) {
    {
      const int rr = tid >> 3, c4 = (tid & 7) << 2;
      const float4 v = *reinterpret_cast<const float4*>(&X[(size_t)(b0 + rr) * xs + k0 + c4]);
      Xs[rr][c4 + 0] = v.x; Xs[rr][c4 + 1] = v.y; Xs[rr][c4 + 2] = v.z; Xs[rr][c4 + 3] = v.w;
    }
    if (tid < 128) {
      const int rr = tid >> 3, c4 = (tid & 7) << 2;
      const float4 v = *reinterpret_cast<const float4*>(&W[(size_t)(n0 + rr) * K + k0 + c4]);
      Ws[rr][c4 + 0] = v.x; Ws[rr][c4 + 1] = v.y; Ws[rr][c4 + 2] = v.z; Ws[rr][c4 + 3] = v.w;
    }
    __syncthreads();
    #pragma unroll
    for (int k = 0; k < 32; ++k) {
      const float wv = Ws[nn][k];
      acc0 = fmaf(Xs[bg][k], wv, acc0);
      acc1 = fmaf(Xs[bg + 16][k], wv, acc1);
    }
    __syncthreads();
  }
  if (relu) { acc0 = fmaxf(acc0, 0.0f); acc1 = fmaxf(acc1, 0.0f); }
  const int ba = b0 + bg, bb = b0 + bg + 16;
  out1[(size_t)ba * o1s + n] = acc0;
  out1[(size_t)bb * o1s + n] = acc1;
  if (out2 != nullptr) {
    out2[(size_t)ba * o2s + n] = acc0;
    out2[(size_t)bb * o2s + n] = acc1;
  }
}

// ---------------- host launch ----------------

extern "C" void kernel_launch(void* const* d_in, const int* in_sizes, int n_in,
                              void* d_out, int out_size, void* d_ws, size_t ws_size,
                              hipStream_t stream) {
  (void)n_in;
  const float* ctx  = (const float*)d_in[0];
  const float* wih0 = (const float*)d_in[1];
  const float* whh0 = (const float*)d_in[2];
  const float* bih0 = (const float*)d_in[3];
  const float* bhh0 = (const float*)d_in[4];
  const float* wih1 = (const float*)d_in[5];
  const float* whh1 = (const float*)d_in[6];
  const float* bih1 = (const float*)d_in[7];
  const float* bhh1 = (const float*)d_in[8];
  const float* w1   = (const float*)d_in[9];
  const float* bp1  = (const float*)d_in[10];
  const float* w2   = (const float*)d_in[11];
  const float* bp2  = (const float*)d_in[12];

  const int T_in   = in_sizes[0] / (B * LATENT);
  const int n_pred = out_size / (B * LATENT);
  float* out = (float*)d_out;

  // ---- ws layout ----
  size_t cur = 0;
  auto alloc = [&](size_t bytes) -> void* {
    void* p = (char*)d_ws + cur;
    cur += (bytes + 255) & ~(size_t)255;
    return p;
  };
  const int E_wih0 = 3 * H * LATENT, E_whh0 = 3 * H * H;
  const int E_wih1 = 3 * H * H, E_whh1 = 3 * H * H;
  const int E_w1 = H * H, E_w2 = LATENT * H;
  const int E_wf = 3 * H * H;
  const int E_ctx = in_sizes[0];

  ushort_t* wih0h = (ushort_t*)alloc(E_wih0 * 2);
  ushort_t* whh0h = (ushort_t*)alloc(E_whh0 * 2);
  ushort_t* wih1h = (ushort_t*)alloc(E_wih1 * 2);
  ushort_t* whh1h = (ushort_t*)alloc(E_whh1 * 2);
  ushort_t* w1h   = (ushort_t*)alloc(E_w1 * 2);
  ushort_t* w2h   = (ushort_t*)alloc(E_w2 * 2);
  ushort_t* wfh   = (ushort_t*)alloc((size_t)E_wf * 2);
  ushort_t* ctxh  = (ushort_t*)alloc((size_t)E_ctx * 2);
  ushort_t* ctxl  = (ushort_t*)alloc((size_t)E_ctx * 2);
  ushort_t* h0Ahi = (ushort_t*)alloc((size_t)T_in * BH * 2);
  ushort_t* h0Alo = (ushort_t*)alloc((size_t)T_in * BH * 2);
  float* bf0 = (float*)alloc(3 * H * 4);
  size_t zero_start = cur;
  float* h0f[2]; float* h1f[2];
  ushort_t* h0hi[2]; ushort_t* h0lo[2]; ushort_t* h1hi[2]; ushort_t* h1lo[2];
  h0f[0] = (float*)alloc(BH * 4); h0f[1] = (float*)alloc(BH * 4);
  h1f[0] = (float*)alloc(BH * 4); h1f[1] = (float*)alloc(BH * 4);
  h0hi[0] = (ushort_t*)alloc(BH * 2); h0lo[0] = (ushort_t*)alloc(BH * 2);
  h0hi[1] = (ushort_t*)alloc(BH * 2); h0lo[1] = (ushort_t*)alloc(BH * 2);
  h1hi[0] = (ushort_t*)alloc(BH * 2); h1lo[0] = (ushort_t*)alloc(BH * 2);
  h1hi[1] = (ushort_t*)alloc(BH * 2); h1lo[1] = (ushort_t*)alloc(BH * 2);
  unsigned* bar = (unsigned*)alloc(16384);
  size_t zero_bytes = cur - zero_start;
  size_t required = cur;

  if (ws_size >= required && n_pred <= T_in) {
    auto splitA = [&](const float* s, ushort_t* hi, ushort_t* lo, int n) {
      int blocks = (n + 255) / 256; if (blocks > 2048) blocks = 2048;
      split_kernel<<<blocks, 256, 0, stream>>>(s, hi, lo, n);
    };
    auto splitW = [&](const float* s, ushort_t* hi, int n) {
      int blocks = (n + 255) / 256; if (blocks > 2048) blocks = 2048;
      split_hi_kernel<<<blocks, 256, 0, stream>>>(s, hi, n);
    };
    splitW(wih0, wih0h, E_wih0);
    splitW(whh0, whh0h, E_whh0);
    splitW(wih1, wih1h, E_wih1);
    splitW(whh1, whh1h, E_whh1);
    splitW(w1, w1h, E_w1);
    splitW(w2, w2h, E_w2);
    wf_kernel<<<dim3(3 * H / 32, H / 32), 256, 0, stream>>>(wih0, w2, wfh);
    bias_fuse_kernel<<<(3 * H + 255) / 256, 256, 0, stream>>>(wih0, bp2, bih0, bf0);
    splitA(ctx, ctxh, ctxl, E_ctx);
    {
      int n4 = (int)(zero_bytes / 16);
      zero4_kernel<<<2048, 256, 0, stream>>>((float4*)((char*)d_ws + zero_start), n4);
    }

    PParams P;
    P.ctxh = ctxh; P.ctxl = ctxl;
    P.wih0h = wih0h; P.whh0h = whh0h;
    P.wih1h = wih1h; P.whh1h = whh1h;
    P.w1h = w1h; P.wfh = wfh;
    P.bih0 = bih0; P.bhh0 = bhh0; P.bih1 = bih1; P.bhh1 = bhh1; P.bp1 = bp1;
    P.bf0 = bf0;
    P.h0f0 = h0f[0]; P.h0f1 = h0f[1]; P.h1f0 = h1f[0]; P.h1f1 = h1f[1];
    P.h0hi0 = h0hi[0]; P.h0lo0 = h0lo[0]; P.h0hi1 = h0hi[1]; P.h0lo1 = h0lo[1];
    P.h1hi0 = h1hi[0]; P.h1lo0 = h1lo[0]; P.h1hi1 = h1hi[1]; P.h1lo1 = h1lo[1];
    P.h0Ahi = h0Ahi; P.h0Alo = h0Alo;
    P.bar = bar;
    P.T_in = T_in; P.n_pred = n_pred; P.ctx_pitch = T_in * LATENT;

    gru_persistent<<<256, 256, 0, stream>>>(P);

    const int rowtiles = (n_pred * B) / 32;
    proj_out_kernel<<<rowtiles * 16, 256, 0, stream>>>(h0Ahi, h0Alo, w2h, bp2, out, n_pred);
    return;
  }

  // ---------- fp32 fallback path (round-1) ----------
  float* ws = (float*)d_ws;
  float* h0a = ws;
  float* h0b = h0a + (size_t)BH;
  float* h1a = h0b + (size_t)BH;
  float* h1b = h1a + (size_t)BH;
  float* p   = h1b + (size_t)BH;
  {
    int n4 = (4 * BH) / 4;
    zero4_kernel<<<256, 256, 0, stream>>>((float4*)h0a, n4);
  }
  float* y = p + (size_t)BH;
  float* h0p = h0a; float* h0n = h0b;
  float* h1p = h1a; float* h1n = h1b;
  const dim3 cgrid(4, 64);
  for (int t = 0; t < T_in; ++t) {
    const float* x = ctx + (size_t)t * LATENT;
    gru_cell_kernel<<<cgrid, 256, 0, stream>>>(x, T_in * LATENT, LATENT,
                                               h0p, wih0, whh0, bih0, bhh0, h0n);
    gru_cell_kernel<<<cgrid, 256, 0, stream>>>(h0n, H, H,
                                               h1p, wih1, whh1, bih1, bhh1, h1n);
    float* tmp;
    tmp = h0p; h0p = h0n; h0n = tmp;
    tmp = h1p; h1p = h1n; h1n = tmp;
  }
  for (int t = 0; t < n_pred; ++t) {
    const float* x; int xstride;
    if (t == 0) { x = ctx + (size_t)(T_in - 1) * LATENT; xstride = T_in * LATENT; }
    else        { x = y; xstride = LATENT; }
    gru_cell_kernel<<<cgrid, 256, 0, stream>>>(x, xstride, LATENT,
                                               h0p, wih0, whh0, bih0, bhh0, h0n);
    gru_cell_kernel<<<cgrid, 256, 0, stream>>>(h0n, H, H,
                                               h1p, wih1, whh1, bih1, bhh1, h1n);
    gemm_bias_kernel<<<dim3(4, H / 16), 256, 0, stream>>>(h1n, H, H, w1, bp1,
                                                          p, H, nullptr, 0, 1);
    gemm_bias_kernel<<<dim3(4, LATENT / 16), 256, 0, stream>>>(p, H, H, w2, bp2,
                                                               y, LATENT,
                                                               out + (size_t)t * LATENT,
                                                               n_pred * LATENT, 0);
    float* tmp;
    tmp = h0p; h0p = h0n; h0n = tmp;
    tmp = h1p; h1p = h1n; h1n = tmp;
  }
}

// Round 18
// 6099.366 us; speedup vs baseline: 1.1361x; 1.0602x over previous
//
#include <hip/hip_runtime.h>
#include <math.h>

#define B 128
#define LATENT 512
#define H 1024
#define BH (B * H)

typedef unsigned short ushort_t;
typedef unsigned int uint_t;
typedef __bf16 bf16x8 __attribute__((ext_vector_type(8)));
typedef float f32x4 __attribute__((ext_vector_type(4)));

#define AS1 __attribute__((address_space(1)))
#define AS3 __attribute__((address_space(3)))

// ---------------- common small kernels ----------------

__global__ __launch_bounds__(256) void zero4_kernel(float4* __restrict__ p, int n4) {
  int i = blockIdx.x * blockDim.x + threadIdx.x;
  int stride = gridDim.x * blockDim.x;
  float4 z = {0.f, 0.f, 0.f, 0.f};
  for (; i < n4; i += stride) p[i] = z;
}

__device__ __forceinline__ void split_bf16(float f, ushort_t& h, ushort_t& l) {
  uint_t u = __float_as_uint(f);
  uint_t hb = (u + 0x7FFFu + ((u >> 16) & 1u)) >> 16;
  float fh = __uint_as_float(hb << 16);
  float r = f - fh;
  uint_t v = __float_as_uint(r);
  uint_t lb = (v + 0x7FFFu + ((v >> 16) & 1u)) >> 16;
  h = (ushort_t)hb; l = (ushort_t)lb;
}

__global__ __launch_bounds__(256) void split_kernel(const float* __restrict__ src,
                                                    ushort_t* __restrict__ hi,
                                                    ushort_t* __restrict__ lo, int n) {
  int i = blockIdx.x * blockDim.x + threadIdx.x;
  int stride = gridDim.x * blockDim.x;
  for (; i < n; i += stride) {
    ushort_t h, l;
    split_bf16(src[i], h, l);
    hi[i] = h; lo[i] = l;
  }
}

__global__ __launch_bounds__(256) void split_hi_kernel(const float* __restrict__ src,
                                                       ushort_t* __restrict__ hi, int n) {
  int i = blockIdx.x * blockDim.x + threadIdx.x;
  int stride = gridDim.x * blockDim.x;
  for (; i < n; i += stride) {
    uint_t u = __float_as_uint(src[i]);
    hi[i] = (ushort_t)((u + 0x7FFFu + ((u >> 16) & 1u)) >> 16);
  }
}

// wf = wih0 @ w2  (fp32 GEMM, hi split)
__global__ __launch_bounds__(256) void wf_kernel(const float* __restrict__ wih0,
                                                 const float* __restrict__ w2,
                                                 ushort_t* __restrict__ wfh) {
  __shared__ float As[32][33];
  __shared__ float Bs[32][33];
  const int i0 = blockIdx.x * 32;
  const int k0 = blockIdx.y * 32;
  const int tid = threadIdx.x;
  const int r = tid >> 3, c4 = (tid & 7) << 2;
  float acc[4] = {0.f, 0.f, 0.f, 0.f};
  for (int m0 = 0; m0 < LATENT; m0 += 32) {
    {
      const float4 v = *reinterpret_cast<const float4*>(&wih0[(size_t)(i0 + r) * LATENT + m0 + c4]);
      As[r][c4] = v.x; As[r][c4 + 1] = v.y; As[r][c4 + 2] = v.z; As[r][c4 + 3] = v.w;
      const float4 w = *reinterpret_cast<const float4*>(&w2[(size_t)(m0 + r) * H + k0 + c4]);
      Bs[r][c4] = w.x; Bs[r][c4 + 1] = w.y; Bs[r][c4 + 2] = w.z; Bs[r][c4 + 3] = w.w;
    }
    __syncthreads();
    #pragma unroll
    for (int mm = 0; mm < 32; ++mm) {
      const float a = As[r][mm];
      #pragma unroll
      for (int x = 0; x < 4; ++x) acc[x] = fmaf(a, Bs[mm][c4 + x], acc[x]);
    }
    __syncthreads();
  }
  #pragma unroll
  for (int x = 0; x < 4; ++x) {
    uint_t u = __float_as_uint(acc[x]);
    wfh[(size_t)(i0 + r) * H + k0 + c4 + x] =
        (ushort_t)((u + 0x7FFFu + ((u >> 16) & 1u)) >> 16);
  }
}

// bf0[g] = bih0[g] + dot(wih0[g,:], bp2)
__global__ __launch_bounds__(256) void bias_fuse_kernel(const float* __restrict__ wih0,
                                                        const float* __restrict__ bp2,
                                                        const float* __restrict__ bih0,
                                                        float* __restrict__ bf0) {
  int g = blockIdx.x * blockDim.x + threadIdx.x;
  if (g < 3 * H) {
    float s = bih0[g];
    const float* row = wih0 + (size_t)g * LATENT;
    #pragma unroll 4
    for (int l = 0; l < LATENT; ++l) s = fmaf(row[l], bp2[l], s);
    bf0[g] = s;
  }
}

__device__ __forceinline__ float sigmoidf_(float v) { return 1.0f / (1.0f + expf(-v)); }

// ---------------- hierarchical grid barrier (acq-rel, r15 known-good) ----------------
__device__ __forceinline__ void grid_barrier(unsigned* bar, int tid, int bid) {
  __syncthreads();
  if (tid == 0) {
    const int g = bid & 7;
    unsigned* arr    = bar + (g << 6);
    unsigned* rel    = bar + 1024 + (g << 6);
    unsigned* master = bar + 2048;
    unsigned gen = __hip_atomic_load(rel, __ATOMIC_RELAXED, __HIP_MEMORY_SCOPE_AGENT);
    unsigned a = __hip_atomic_fetch_add(arr, 1u, __ATOMIC_ACQ_REL, __HIP_MEMORY_SCOPE_AGENT);
    if (a == 31u) {
      __hip_atomic_store(arr, 0u, __ATOMIC_RELAXED, __HIP_MEMORY_SCOPE_AGENT);
      unsigned m = __hip_atomic_fetch_add(master, 1u, __ATOMIC_ACQ_REL, __HIP_MEMORY_SCOPE_AGENT);
      if (m == 7u) {
        __hip_atomic_store(master, 0u, __ATOMIC_RELAXED, __HIP_MEMORY_SCOPE_AGENT);
        #pragma unroll
        for (int i = 0; i < 8; ++i)
          __hip_atomic_fetch_add(bar + 1024 + (i << 6), 1u, __ATOMIC_ACQ_REL, __HIP_MEMORY_SCOPE_AGENT);
      }
    }
    while (__hip_atomic_load(rel, __ATOMIC_RELAXED, __HIP_MEMORY_SCOPE_AGENT) == gen)
      __builtin_amdgcn_s_sleep(1);
    (void)__hip_atomic_load(rel, __ATOMIC_ACQUIRE, __HIP_MEMORY_SCOPE_AGENT);
  }
  __syncthreads();
}

#define WAIT_VM(N) asm volatile("s_waitcnt vmcnt(" #N ")" ::: "memory")

// ---------------- one GEMM phase: counted-vmcnt 3-ring pipeline (T3/T4) ----------------
// 32 rows x NJ*16 cols x NG gates; 128-wide chunks; 3-deep LDS ring, depth-2
// prefetch. Per chunk: {vmcnt(2*NSLOT) -> s_barrier -> MFMA -> lgkmcnt(0) ->
// s_barrier -> issue c+3}. Loads never drained to 0 in the loop.
template <int NJ, int NG, int PH, int EPI>
__device__ __forceinline__ void phase_mm(
    char* smem, const int tid, const int Mb, const int jb, const bool active,
    const ushort_t* aAh, const ushort_t* aAl, int aApitch, int K1,
    const ushort_t* wAh,
    const ushort_t* aBh, const ushort_t* aBl, int aBpitch, int K2,
    const ushort_t* wBh,
    const float* bih, const float* bhh,
    const float* h_prev, float* h_out,
    ushort_t* out_hi, ushort_t* out_lo, int split_pitch,
    const float* bias, float* out_f32)
{
  if (!active) return;
  constexpr int NW = NJ * NG;
  constexpr int NSLOT = 4 + NW;          // A hi(2)+lo(2) + W(NW); 4KB slots
  constexpr int BUFB = NSLOT * 4096;
  constexpr int NPG = PH * NW;
  constexpr int CW = NJ * 16;

  const int b0 = Mb * 32;
  const int j0 = jb * CW;
  const int NC1 = K1 >> 7;               // always >= 4 in this model
  const int NC2 = (PH == 2) ? (K2 >> 7) : 0;
  const int NC = NC1 + NC2;

  const char* g[NSLOT];
  auto build = [&](const ushort_t* ah, const ushort_t* al, int apitch,
                   const ushort_t* wh, int K) {
    const int rowt = tid >> 4;
    const int cp = tid & 15;
    const int cc = cp ^ rowt;
    #pragma unroll
    for (int u = 0; u < NSLOT; ++u) {
      const ushort_t* basep; size_t off;
      if (u < 2)      { basep = ah; off = (size_t)(b0 + u * 16 + rowt) * apitch + cc * 8; }
      else if (u < 4) { basep = al; off = (size_t)(b0 + (u - 2) * 16 + rowt) * apitch + cc * 8; }
      else {
        const int w = u - 4, jt = w % NJ, gate = w / NJ;
        const int wrow = (NG == 3) ? (gate * H + j0 + jt * 16 + rowt) : (j0 + jt * 16 + rowt);
        basep = wh; off = (size_t)wrow * K + cc * 8;
      }
      g[u] = (const char*)(basep + off);
    }
  };
  build(aAh, aAl, aApitch, wAh, K1);

  const int s = tid >> 6;
  const int q = (tid >> 4) & 3;
  const int r = tid & 15;
  const int gs = (((4 * s + q) ^ r) << 4);
  const int offA00 = r * 256 + gs;
  const int offA01 = 4096 + r * 256 + gs;
  const int offA10 = 8192 + r * 256 + gs;
  const int offA11 = 12288 + r * 256 + gs;
  int offW[NW];
  #pragma unroll
  for (int w = 0; w < NW; ++w) offW[w] = (4 + w) * 4096 + r * 256 + gs;

  f32x4 accA[NJ][NG][2];
  f32x4 accB[NJ][NG][2];
  #pragma unroll
  for (int jt = 0; jt < NJ; ++jt)
    #pragma unroll
    for (int gg = 0; gg < NG; ++gg)
      #pragma unroll
      for (int mf = 0; mf < 2; ++mf) {
        accA[jt][gg][mf] = (f32x4){0.f, 0.f, 0.f, 0.f};
        accB[jt][gg][mf] = (f32x4){0.f, 0.f, 0.f, 0.f};
      }

  const unsigned wofs = (unsigned)(tid >> 6) * 1024;
  auto issue = [&](int cc2) {
    const bool isB = (PH == 2) && (cc2 >= NC1);
    const int koff = (isB ? (cc2 - NC1) : cc2) * 256;
    char* dst = smem + (cc2 % 3) * BUFB + wofs;
    #pragma unroll
    for (int u = 0; u < NSLOT; ++u)
      __builtin_amdgcn_global_load_lds(
          (const AS1 void*)(g[u] + koff),
          (AS3 void*)(dst + u * 4096), 16, 0, 0);
  };

  auto compute = [&](int slot, f32x4 (&acc)[NJ][NG][2]) {
    const char* base = smem + slot * BUFB;
    bf16x8 ah0 = *(const bf16x8*)(base + offA00);
    bf16x8 ah1 = *(const bf16x8*)(base + offA01);
    bf16x8 al0 = *(const bf16x8*)(base + offA10);
    bf16x8 al1 = *(const bf16x8*)(base + offA11);
    #pragma unroll
    for (int gg = 0; gg < NG; ++gg)
      #pragma unroll
      for (int jt = 0; jt < NJ; ++jt) {
        const int w = gg * NJ + jt;
        bf16x8 wh = *(const bf16x8*)(base + offW[w]);
        acc[jt][gg][0] = __builtin_amdgcn_mfma_f32_16x16x32_bf16(ah0, wh, acc[jt][gg][0], 0, 0, 0);
        acc[jt][gg][0] = __builtin_amdgcn_mfma_f32_16x16x32_bf16(al0, wh, acc[jt][gg][0], 0, 0, 0);
        acc[jt][gg][1] = __builtin_amdgcn_mfma_f32_16x16x32_bf16(ah1, wh, acc[jt][gg][1], 0, 0, 0);
        acc[jt][gg][1] = __builtin_amdgcn_mfma_f32_16x16x32_bf16(al1, wh, acc[jt][gg][1], 0, 0, 0);
      }
  };

  // prologue: 3 chunks in flight (NC1 >= 4 so these are all A-phase)
  issue(0);
  if (NC > 1) issue(1);
  if (NC > 2) issue(2);

  #pragma unroll 1
  for (int c = 0; c < NC; ++c) {
    {
      const int rem = NC - 1 - c;   // chunks in flight beyond c
      if (rem <= 0) {
        WAIT_VM(0);
      } else if (rem == 1) {
        if constexpr (NSLOT == 10)      WAIT_VM(10);
        else if constexpr (NSLOT == 7)  WAIT_VM(7);
        else if constexpr (NSLOT == 6)  WAIT_VM(6);
        else                            WAIT_VM(5);
      } else {
        if constexpr (NSLOT == 10)      WAIT_VM(20);
        else if constexpr (NSLOT == 7)  WAIT_VM(14);
        else if constexpr (NSLOT == 6)  WAIT_VM(12);
        else                            WAIT_VM(10);
      }
    }
    __builtin_amdgcn_s_barrier();        // chunk c visible to all waves
    if (PH == 1 || c < NC1) compute(c % 3, accA);
    else                    compute(c % 3, accB);
    if (c + 3 < NC) {
      asm volatile("s_waitcnt lgkmcnt(0)" ::: "memory");  // my ds_reads of slot c%3 done
      __builtin_amdgcn_s_barrier();                       // all waves done reading slot c%3
      if (PH == 2 && c + 3 == NC1) build(aBh, aBl, aBpitch, wBh, K2);
      issue(c + 3);                                       // overwrites slot c%3
    }
  }
  __syncthreads();

  // ---- cross-wave reduce (alias smem) ----
  const int lane = tid & 63;
  #pragma unroll
  for (int gg = 0; gg < NG; ++gg)
    #pragma unroll
    for (int jt = 0; jt < NJ; ++jt)
      #pragma unroll
      for (int mf = 0; mf < 2; ++mf) {
        const int w = gg * NJ + jt;
        *(f32x4*)(smem + (size_t)(((s * NPG + w) * 2 + mf) * 64 + lane) * 16) = accA[jt][gg][mf];
        if (PH == 2)
          *(f32x4*)(smem + (size_t)(((s * NPG + NW + w) * 2 + mf) * 64 + lane) * 16) = accB[jt][gg][mf];
      }
  __syncthreads();

  for (int o = tid; o < 32 * CW; o += 256) {
    const int row = o / CW, c = o % CW;
    const int jt = c >> 4, cr = c & 15;
    const int mf = row >> 4, br = row & 15, qq = br >> 2, rg = br & 3;
    const int ln = cr + qq * 16;
    float v[PH * NG];
    #pragma unroll
    for (int pg = 0; pg < PH * NG; ++pg) {
      const int w = (pg < NG) ? (pg * NJ + jt) : (NW + (pg - NG) * NJ + jt);
      float sum = 0.f;
      #pragma unroll
      for (int ss = 0; ss < 4; ++ss)
        sum += *(const float*)(smem + (size_t)(((ss * NPG + w) * 2 + mf) * 64 + ln) * 16 + rg * 4);
      v[pg] = sum;
    }
    const int bglob = b0 + row, jglob = j0 + c;
    if (EPI == 0) {
      float ir = v[0] + bih[jglob];
      float iz = v[1] + bih[H + jglob];
      float in_ = v[2] + bih[2 * H + jglob];
      float hr = v[3] + bhh[jglob];
      float hz = v[4] + bhh[H + jglob];
      float hn = v[5] + bhh[2 * H + jglob];
      float rr_ = sigmoidf_(ir + hr);
      float zz_ = sigmoidf_(iz + hz);
      float nn_ = tanhf(in_ + rr_ * hn);
      float hp = h_prev[(size_t)bglob * H + jglob];
      float ho = (1.f - zz_) * nn_ + zz_ * hp;
      h_out[(size_t)bglob * H + jglob] = ho;
      ushort_t hb, lb;
      split_bf16(ho, hb, lb);
      out_hi[(size_t)bglob * H + jglob] = hb;
      out_lo[(size_t)bglob * H + jglob] = lb;
    } else if (EPI == 1) {
      float vv = v[0] + bias[jglob];
      vv = fmaxf(vv, 0.f);
      ushort_t hb, lb;
      split_bf16(vv, hb, lb);
      out_hi[(size_t)bglob * split_pitch + jglob] = hb;
      out_lo[(size_t)bglob * split_pitch + jglob] = lb;
    } else {
      float vv = v[0] + bias[jglob];
      const int tt = bglob >> 7, bb2 = bglob & 127;
      out_f32[((size_t)bb2 * split_pitch + tt) * LATENT + jglob] = vv;
    }
  }
  __syncthreads();
}

// ---------------- persistent kernel: 65 enc + 192 dec phases, XCD-clustered ----------------

struct PParams {
  const ushort_t *ctxh, *ctxl;
  const ushort_t *wih0h, *whh0h;
  const ushort_t *wih1h, *whh1h;
  const ushort_t *w1h;
  const ushort_t *wfh;
  const float *bih0, *bhh0, *bih1, *bhh1, *bp1;
  const float *bf0;
  float *h0f0, *h0f1, *h1f0, *h1f1;
  ushort_t *h0hi0, *h0lo0, *h0hi1, *h0lo1;
  ushort_t *h1hi0, *h1lo0, *h1hi1, *h1lo1;
  ushort_t *h0Ahi, *h0Alo;      // [T_in][B][H]; aliased as pA in decoder
  unsigned* bar;
  int T_in, n_pred, ctx_pitch;
};

__global__ __launch_bounds__(256, 1) void gru_persistent(PParams P) {
  __shared__ char smem[122880];   // 3-ring x 40KB (encoder); decoder/DP use less
  const int tid = threadIdx.x;
  const int bid = blockIdx.x;

  float* h0f[2] = {P.h0f0, P.h0f1};
  float* h1f[2] = {P.h1f0, P.h1f1};
  ushort_t* h0hi[2] = {P.h0hi0, P.h0hi1};
  ushort_t* h0lo[2] = {P.h0lo0, P.h0lo1};
  ushort_t* h1hi[2] = {P.h1hi0, P.h1hi1};
  ushort_t* h1lo[2] = {P.h1lo0, P.h1lo1};

  int p0 = 0, p1 = 0;

  // -------- pipelined encoder: L0 (blocks 0-127) || L1 (128-255), XCD-clustered --------
  const int idx = (bid < 128) ? bid : (bid - 128);
  const int eMb = (idx >> 5) & 3;
  const int ejb = (idx & 7) * 4 + ((idx >> 3) & 3);
  #pragma unroll 1
  for (int p = 0; p <= P.T_in; ++p) {
    const int n0 = p0 ^ 1, n1 = p1 ^ 1;
    if (bid < 128) {
      if (p < P.T_in) {
        const int t = p;
        phase_mm<2, 3, 2, 0>(smem, tid, eMb, ejb, true,
            P.ctxh + (size_t)t * LATENT, P.ctxl + (size_t)t * LATENT, P.ctx_pitch, LATENT,
            P.wih0h,
            (t == 0) ? P.h0hi0 : P.h0Ahi + (size_t)(t - 1) * BH,
            (t == 0) ? P.h0lo0 : P.h0Alo + (size_t)(t - 1) * BH, H, H, P.whh0h,
            P.bih0, P.bhh0, h0f[p0], h0f[n0],
            P.h0Ahi + (size_t)t * BH, P.h0Alo + (size_t)t * BH, H, nullptr, nullptr);
      }
    } else {
      if (p >= 1) {
        const int t = p - 1;
        phase_mm<2, 3, 2, 0>(smem, tid, eMb, ejb, true,
            P.h0Ahi + (size_t)t * BH, P.h0Alo + (size_t)t * BH, H, H,
            P.wih1h,
            h1hi[p1], h1lo[p1], H, H, P.whh1h,
            P.bih1, P.bhh1, h1f[p1], h1f[n1],
            h1hi[n1], h1lo[n1], H, nullptr, nullptr);
      }
    }
    grid_barrier(P.bar, tid, bid);
    if (p < P.T_in) p0 = n0;
    if (p >= 1) p1 = n1;
  }

  // -------- decoder: {D0 fused, D1, DP}, XCD-clustered --------
  const int dMb = (bid >> 6) & 3;
  const int djb = (bid & 7) * 8 + ((bid >> 3) & 7);
  const ushort_t* d0ph = P.h0Ahi + (size_t)(P.T_in - 1) * BH;
  const ushort_t* d0pl = P.h0Alo + (size_t)(P.T_in - 1) * BH;
  ushort_t* pAh = P.h0Ahi;
  ushort_t* pAl = P.h0Alo;
  #pragma unroll 1
  for (int t = 0; t < P.n_pred; ++t) {
    const int n0 = p0 ^ 1;
    if (t == 0) {
      phase_mm<1, 3, 2, 0>(smem, tid, dMb, djb, true,
          P.ctxh + (size_t)(P.T_in - 1) * LATENT, P.ctxl + (size_t)(P.T_in - 1) * LATENT,
          P.ctx_pitch, LATENT,
          P.wih0h,
          d0ph, d0pl, H, H, P.whh0h,
          P.bih0, P.bhh0, h0f[p0], h0f[n0], h0hi[n0], h0lo[n0], H, nullptr, nullptr);
    } else {
      phase_mm<1, 3, 2, 0>(smem, tid, dMb, djb, true,
          pAh + (size_t)(t - 1) * BH, pAl + (size_t)(t - 1) * BH, H, H,
          P.wfh,
          d0ph, d0pl, H, H, P.whh0h,
          P.bf0, P.bhh0, h0f[p0], h0f[n0], h0hi[n0], h0lo[n0], H, nullptr, nullptr);
    }
    grid_barrier(P.bar, tid, bid);
    d0ph = h0hi[n0]; d0pl = h0lo[n0];
    const int n1 = p1 ^ 1;
    phase_mm<1, 3, 2, 0>(smem, tid, dMb, djb, true,
        h0hi[n0], h0lo[n0], H, H,
        P.wih1h,
        h1hi[p1], h1lo[p1], H, H, P.whh1h,
        P.bih1, P.bhh1, h1f[p1], h1f[n1], h1hi[n1], h1lo[n1], H, nullptr, nullptr);
    grid_barrier(P.bar, tid, bid);
    phase_mm<1, 1, 1, 1>(smem, tid, dMb, djb, true,
        h1hi[n1], h1lo[n1], H, H,
        P.w1h,
        nullptr, nullptr, 0, 0, nullptr,
        nullptr, nullptr, nullptr, nullptr,
        pAh + (size_t)t * BH, pAl + (size_t)t * BH, H, P.bp1, nullptr);
    grid_barrier(P.bar, tid, bid);
    p0 = n0; p1 = n1;
  }
}

// ---------------- final ys GEMM (parallel) ----------------
__global__ __launch_bounds__(256, 2) void proj_out_kernel(
    const ushort_t* __restrict__ pAh, const ushort_t* __restrict__ pAl,
    const ushort_t* __restrict__ w2h, const float* __restrict__ bp2,
    float* __restrict__ out, int n_pred)
{
  __shared__ char smem[73728];   // 3-ring x 24KB (NSLOT=6)
  const int tid = threadIdx.x;
  const int rt = blockIdx.x >> 4;
  const int ct = blockIdx.x & 15;
  phase_mm<2, 1, 1, 3>(smem, tid, rt, ct, true,
      pAh, pAl, H, H,
      w2h,
      nullptr, nullptr, 0, 0, nullptr,
      nullptr, nullptr, nullptr, nullptr,
      nullptr, nullptr, n_pred, bp2, out);
}

// ---------------- fp32 fallback (round-1, known-good) ----------------

__global__ __launch_bounds__(256) void gru_cell_kernel(
    const float* __restrict__ x, int xs, int Kih,
    const float* __restrict__ h_prev,
    const float* __restrict__ wih, const float* __restrict__ whh,
    const float* __restrict__ bih, const float* __restrict__ bhh,
    float* __restrict__ h_out)
{
  __shared__ float Xs[32][33];
  __shared__ float Ws[48][33];
  const int tid = threadIdx.x;
  const int b0 = blockIdx.x * 32;
  const int j0 = blockIdx.y * 16;
  const int bg = tid & 15;
  const int jj = tid >> 4;
  const int j = j0 + jj;
  float accA[2][3];
  float accB[2][3];
  #pragma unroll
  for (int g = 0; g < 3; ++g) {
    const float bi = bih[g * H + j];
    const float bh = bhh[g * H + j];
    accA[0][g] = bi; accA[1][g] = bi;
    accB[0][g] = bh; accB[1][g] = bh;
  }
  for (int k0 = 0; k0 < Kih; k0 += 32) {
    {
      const int rr = tid >> 3, c4 = (tid & 7) << 2;
      const float4 v = *reinterpret_cast<const float4*>(&x[(size_t)(b0 + rr) * xs + k0 + c4]);
      Xs[rr][c4 + 0] = v.x; Xs[rr][c4 + 1] = v.y; Xs[rr][c4 + 2] = v.z; Xs[rr][c4 + 3] = v.w;
    }
    for (int li = tid; li < 48 * 8; li += 256) {
      const int rr = li >> 3, c4 = (li & 7) << 2;
      const int g = rr >> 4, jr = rr & 15;
      const float4 v = *reinterpret_cast<const float4*>(&wih[(size_t)(g * H + j0 + jr) * Kih + k0 + c4]);
      Ws[rr][c4 + 0] = v.x; Ws[rr][c4 + 1] = v.y; Ws[rr][c4 + 2] = v.z; Ws[rr][c4 + 3] = v.w;
    }
    __syncthreads();
    #pragma unroll
    for (int k = 0; k < 32; ++k) {
      const float x0 = Xs[bg][k];
      const float x1 = Xs[bg + 16][k];
      #pragma unroll
      for (int g = 0; g < 3; ++g) {
        const float wv = Ws[g * 16 + jj][k];
        accA[0][g] = fmaf(x0, wv, accA[0][g]);
        accA[1][g] = fmaf(x1, wv, accA[1][g]);
      }
    }
    __syncthreads();
  }
  for (int k0 = 0; k0 < H; k0 += 32) {
    {
      const int rr = tid >> 3, c4 = (tid & 7) << 2;
      const float4 v = *reinterpret_cast<const float4*>(&h_prev[(size_t)(b0 + rr) * H + k0 + c4]);
      Xs[rr][c4 + 0] = v.x; Xs[rr][c4 + 1] = v.y; Xs[rr][c4 + 2] = v.z; Xs[rr][c4 + 3] = v.w;
    }
    for (int li = tid; li < 48 * 8; li += 256) {
      const int rr = li >> 3, c4 = (li & 7) << 2;
      const int g = rr >> 4, jr = rr & 15;
      const float4 v = *reinterpret_cast<const float4*>(&whh[(size_t)(g * H + j0 + jr) * H + k0 + c4]);
      Ws[rr][c4 + 0] = v.x; Ws[rr][c4 + 1] = v.y; Ws[rr][c4 + 2] = v.z; Ws[rr][c4 + 3] = v.w;
    }
    __syncthreads();
    #pragma unroll
    for (int k = 0; k < 32; ++k) {
      const float h0v = Xs[bg][k];
      const float h1v = Xs[bg + 16][k];
      #pragma unroll
      for (int g = 0; g < 3; ++g) {
        const float wv = Ws[g * 16 + jj][k];
        accB[0][g] = fmaf(h0v, wv, accB[0][g]);
        accB[1][g] = fmaf(h1v, wv, accB[1][g]);
      }
    }
    __syncthreads();
  }
  #pragma unroll
  for (int i = 0; i < 2; ++i) {
    const int b = b0 + bg + i * 16;
    const float hp = h_prev[(size_t)b * H + j];
    const float r = sigmoidf_(accA[i][0] + accB[i][0]);
    const float z = sigmoidf_(accA[i][1] + accB[i][1]);
    const float n = tanhf(accA[i][2] + r * accB[i][2]);
    h_out[(size_t)b * H + j] = (1.0f - z) * n + z * hp;
  }
}

__global__ __launch_bounds__(256) void gemm_bias_kernel(
    const float* __restrict__ X, int xs, int K,
    const float* __restrict__ W, const float* __restrict__ bias,
    float* __restrict__ out1, int o1s,
    float* __restrict__ out2, int o2s,
    int relu)
{
  __shared__ float Xs[32][33];
  __shared__ float Ws[16][33];
  const int tid = threadIdx.x;
  const int b0 = blockIdx.x * 32;
  const int n0 = blockIdx.y * 16;
  const int bg = tid & 15;
  const int nn = tid >> 4;
  const int n = n0 + nn;
  float acc0 = bias[n];
  float acc1 = acc0;
  for (int k0 = 0; k0 < K; k0 += 32) {
    {
      const int rr = tid >> 3, c4 = (tid & 7) << 2;
      const float4 v = *reinterpret_cast<const float4*>(&X[(size_t)(b0 + rr) * xs + k0 + c4]);
      Xs[rr][c4 + 0] = v.x; Xs[rr][c4 + 1] = v.y; Xs[rr][c4 + 2] = v.z; Xs[rr][c4 + 3] = v.w;
    }
    if (tid < 128) {
      const int rr = tid >> 3, c4 = (tid & 7) << 2;
      const float4 v = *reinterpret_cast<const float4*>(&W[(size_t)(n0 + rr) * K + k0 + c4]);
      Ws[rr][c4 + 0] = v.x; Ws[rr][c4 + 1] = v.y; Ws[rr][c4 + 2] = v.z; Ws[rr][c4 + 3] = v.w;
    }
    __syncthreads();
    #pragma unroll
    for (int k = 0; k < 32; ++k) {
      const float wv = Ws[nn][k];
      acc0 = fmaf(Xs[bg][k], wv, acc0);
      acc1 = fmaf(Xs[bg + 16][k], wv, acc1);
    }
    __syncthreads();
  }
  if (relu) { acc0 = fmaxf(acc0, 0.0f); acc1 = fmaxf(acc1, 0.0f); }
  const int ba = b0 + bg, bb = b0 + bg + 16;
  out1[(size_t)ba * o1s + n] = acc0;
  out1[(size_t)bb * o1s + n] = acc1;
  if (out2 != nullptr) {
    out2[(size_t)ba * o2s + n] = acc0;
    out2[(size_t)bb * o2s + n] = acc1;
  }
}

// ---------------- host launch ----------------

extern "C" void kernel_launch(void* const* d_in, const int* in_sizes, int n_in,
                              void* d_out, int out_size, void* d_ws, size_t ws_size,
                              hipStream_t stream) {
  (void)n_in;
  const float* ctx  = (const float*)d_in[0];
  const float* wih0 = (const float*)d_in[1];
  const float* whh0 = (const float*)d_in[2];
  const float* bih0 = (const float*)d_in[3];
  const float* bhh0 = (const float*)d_in[4];
  const float* wih1 = (const float*)d_in[5];
  const float* whh1 = (const float*)d_in[6];
  const float* bih1 = (const float*)d_in[7];
  const float* bhh1 = (const float*)d_in[8];
  const float* w1   = (const float*)d_in[9];
  const float* bp1  = (const float*)d_in[10];
  const float* w2   = (const float*)d_in[11];
  const float* bp2  = (const float*)d_in[12];

  const int T_in   = in_sizes[0] / (B * LATENT);
  const int n_pred = out_size / (B * LATENT);
  float* out = (float*)d_out;

  // ---- ws layout ----
  size_t cur = 0;
  auto alloc = [&](size_t bytes) -> void* {
    void* p = (char*)d_ws + cur;
    cur += (bytes + 255) & ~(size_t)255;
    return p;
  };
  const int E_wih0 = 3 * H * LATENT, E_whh0 = 3 * H * H;
  const int E_wih1 = 3 * H * H, E_whh1 = 3 * H * H;
  const int E_w1 = H * H, E_w2 = LATENT * H;
  const int E_wf = 3 * H * H;
  const int E_ctx = in_sizes[0];

  ushort_t* wih0h = (ushort_t*)alloc(E_wih0 * 2);
  ushort_t* whh0h = (ushort_t*)alloc(E_whh0 * 2);
  ushort_t* wih1h = (ushort_t*)alloc(E_wih1 * 2);
  ushort_t* whh1h = (ushort_t*)alloc(E_whh1 * 2);
  ushort_t* w1h   = (ushort_t*)alloc(E_w1 * 2);
  ushort_t* w2h   = (ushort_t*)alloc(E_w2 * 2);
  ushort_t* wfh   = (ushort_t*)alloc((size_t)E_wf * 2);
  ushort_t* ctxh  = (ushort_t*)alloc((size_t)E_ctx * 2);
  ushort_t* ctxl  = (ushort_t*)alloc((size_t)E_ctx * 2);
  ushort_t* h0Ahi = (ushort_t*)alloc((size_t)T_in * BH * 2);
  ushort_t* h0Alo = (ushort_t*)alloc((size_t)T_in * BH * 2);
  float* bf0 = (float*)alloc(3 * H * 4);
  size_t zero_start = cur;
  float* h0f[2]; float* h1f[2];
  ushort_t* h0hi[2]; ushort_t* h0lo[2]; ushort_t* h1hi[2]; ushort_t* h1lo[2];
  h0f[0] = (float*)alloc(BH * 4); h0f[1] = (float*)alloc(BH * 4);
  h1f[0] = (float*)alloc(BH * 4); h1f[1] = (float*)alloc(BH * 4);
  h0hi[0] = (ushort_t*)alloc(BH * 2); h0lo[0] = (ushort_t*)alloc(BH * 2);
  h0hi[1] = (ushort_t*)alloc(BH * 2); h0lo[1] = (ushort_t*)alloc(BH * 2);
  h1hi[0] = (ushort_t*)alloc(BH * 2); h1lo[0] = (ushort_t*)alloc(BH * 2);
  h1hi[1] = (ushort_t*)alloc(BH * 2); h1lo[1] = (ushort_t*)alloc(BH * 2);
  unsigned* bar = (unsigned*)alloc(16384);
  size_t zero_bytes = cur - zero_start;
  size_t required = cur;

  if (ws_size >= required && n_pred <= T_in) {
    auto splitA = [&](const float* s, ushort_t* hi, ushort_t* lo, int n) {
      int blocks = (n + 255) / 256; if (blocks > 2048) blocks = 2048;
      split_kernel<<<blocks, 256, 0, stream>>>(s, hi, lo, n);
    };
    auto splitW = [&](const float* s, ushort_t* hi, int n) {
      int blocks = (n + 255) / 256; if (blocks > 2048) blocks = 2048;
      split_hi_kernel<<<blocks, 256, 0, stream>>>(s, hi, n);
    };
    splitW(wih0, wih0h, E_wih0);
    splitW(whh0, whh0h, E_whh0);
    splitW(wih1, wih1h, E_wih1);
    splitW(whh1, whh1h, E_whh1);
    splitW(w1, w1h, E_w1);
    splitW(w2, w2h, E_w2);
    wf_kernel<<<dim3(3 * H / 32, H / 32), 256, 0, stream>>>(wih0, w2, wfh);
    bias_fuse_kernel<<<(3 * H + 255) / 256, 256, 0, stream>>>(wih0, bp2, bih0, bf0);
    splitA(ctx, ctxh, ctxl, E_ctx);
    {
      int n4 = (int)(zero_bytes / 16);
      zero4_kernel<<<2048, 256, 0, stream>>>((float4*)((char*)d_ws + zero_start), n4);
    }

    PParams P;
    P.ctxh = ctxh; P.ctxl = ctxl;
    P.wih0h = wih0h; P.whh0h = whh0h;
    P.wih1h = wih1h; P.whh1h = whh1h;
    P.w1h = w1h; P.wfh = wfh;
    P.bih0 = bih0; P.bhh0 = bhh0; P.bih1 = bih1; P.bhh1 = bhh1; P.bp1 = bp1;
    P.bf0 = bf0;
    P.h0f0 = h0f[0]; P.h0f1 = h0f[1]; P.h1f0 = h1f[0]; P.h1f1 = h1f[1];
    P.h0hi0 = h0hi[0]; P.h0lo0 = h0lo[0]; P.h0hi1 = h0hi[1]; P.h0lo1 = h0lo[1];
    P.h1hi0 = h1hi[0]; P.h1lo0 = h1lo[0]; P.h1hi1 = h1hi[1]; P.h1lo1 = h1lo[1];
    P.h0Ahi = h0Ahi; P.h0Alo = h0Alo;
    P.bar = bar;
    P.T_in = T_in; P.n_pred = n_pred; P.ctx_pitch = T_in * LATENT;

    gru_persistent<<<256, 256, 0, stream>>>(P);

    const int rowtiles = (n_pred * B) / 32;
    proj_out_kernel<<<rowtiles * 16, 256, 0, stream>>>(h0Ahi, h0Alo, w2h, bp2, out, n_pred);
    return;
  }

  // ---------- fp32 fallback path (round-1) ----------
  float* ws = (float*)d_ws;
  float* h0a = ws;
  float* h0b = h0a + (size_t)BH;
  float* h1a = h0b + (size_t)BH;
  float* h1b = h1a + (size_t)BH;
  float* p   = h1b + (size_t)BH;
  {
    int n4 = (4 * BH) / 4;
    zero4_kernel<<<256, 256, 0, stream>>>((float4*)h0a, n4);
  }
  float* y = p + (size_t)BH;
  float* h0p = h0a; float* h0n = h0b;
  float* h1p = h1a; float* h1n = h1b;
  const dim3 cgrid(4, 64);
  for (int t = 0; t < T_in; ++t) {
    const float* x = ctx + (size_t)t * LATENT;
    gru_cell_kernel<<<cgrid, 256, 0, stream>>>(x, T_in * LATENT, LATENT,
                                               h0p, wih0, whh0, bih0, bhh0, h0n);
    gru_cell_kernel<<<cgrid, 256, 0, stream>>>(h0n, H, H,
                                               h1p, wih1, whh1, bih1, bhh1, h1n);
    float* tmp;
    tmp = h0p; h0p = h0n; h0n = tmp;
    tmp = h1p; h1p = h1n; h1n = tmp;
  }
  for (int t = 0; t < n_pred; ++t) {
    const float* x; int xstride;
    if (t == 0) { x = ctx + (size_t)(T_in - 1) * LATENT; xstride = T_in * LATENT; }
    else        { x = y; xstride = LATENT; }
    gru_cell_kernel<<<cgrid, 256, 0, stream>>>(x, xstride, LATENT,
                                               h0p, wih0, whh0, bih0, bhh0, h0n);
    gru_cell_kernel<<<cgrid, 256, 0, stream>>>(h0n, H, H,
                                               h1p, wih1, whh1, bih1, bhh1, h1n);
    gemm_bias_kernel<<<dim3(4, H / 16), 256, 0, stream>>>(h1n, H, H, w1, bp1,
                                                          p, H, nullptr, 0, 1);
    gemm_bias_kernel<<<dim3(4, LATENT / 16), 256, 0, stream>>>(p, H, H, w2, bp2,
                                                               y, LATENT,
                                                               out + (size_t)t * LATENT,
                                                               n_pred * LATENT, 0);
    float* tmp;
    tmp = h0p; h0p = h0n; h0n = tmp;
    tmp = h1p; h1p = h1n; h1n = tmp;
  }
}

// Round 19
// 5943.982 us; speedup vs baseline: 1.1658x; 1.0261x over previous
//
#include <hip/hip_runtime.h>
#include <math.h>

#define B 128
#define LATENT 512
#define H 1024
#define BH (B * H)

typedef unsigned short ushort_t;
typedef unsigned int uint_t;
typedef __bf16 bf16x8 __attribute__((ext_vector_type(8)));
typedef float f32x4 __attribute__((ext_vector_type(4)));

#define AS1 __attribute__((address_space(1)))
#define AS3 __attribute__((address_space(3)))

// ---------------- common small kernels ----------------

__global__ __launch_bounds__(256) void zero4_kernel(float4* __restrict__ p, int n4) {
  int i = blockIdx.x * blockDim.x + threadIdx.x;
  int stride = gridDim.x * blockDim.x;
  float4 z = {0.f, 0.f, 0.f, 0.f};
  for (; i < n4; i += stride) p[i] = z;
}

__device__ __forceinline__ void split_bf16(float f, ushort_t& h, ushort_t& l) {
  uint_t u = __float_as_uint(f);
  uint_t hb = (u + 0x7FFFu + ((u >> 16) & 1u)) >> 16;
  float fh = __uint_as_float(hb << 16);
  float r = f - fh;
  uint_t v = __float_as_uint(r);
  uint_t lb = (v + 0x7FFFu + ((v >> 16) & 1u)) >> 16;
  h = (ushort_t)hb; l = (ushort_t)lb;
}

__global__ __launch_bounds__(256) void split_kernel(const float* __restrict__ src,
                                                    ushort_t* __restrict__ hi,
                                                    ushort_t* __restrict__ lo, int n) {
  int i = blockIdx.x * blockDim.x + threadIdx.x;
  int stride = gridDim.x * blockDim.x;
  for (; i < n; i += stride) {
    ushort_t h, l;
    split_bf16(src[i], h, l);
    hi[i] = h; lo[i] = l;
  }
}

__global__ __launch_bounds__(256) void split_hi_kernel(const float* __restrict__ src,
                                                       ushort_t* __restrict__ hi, int n) {
  int i = blockIdx.x * blockDim.x + threadIdx.x;
  int stride = gridDim.x * blockDim.x;
  for (; i < n; i += stride) {
    uint_t u = __float_as_uint(src[i]);
    hi[i] = (ushort_t)((u + 0x7FFFu + ((u >> 16) & 1u)) >> 16);
  }
}

// wf = wih0 @ w2  (fp32 GEMM, hi split)
__global__ __launch_bounds__(256) void wf_kernel(const float* __restrict__ wih0,
                                                 const float* __restrict__ w2,
                                                 ushort_t* __restrict__ wfh) {
  __shared__ float As[32][33];
  __shared__ float Bs[32][33];
  const int i0 = blockIdx.x * 32;
  const int k0 = blockIdx.y * 32;
  const int tid = threadIdx.x;
  const int r = tid >> 3, c4 = (tid & 7) << 2;
  float acc[4] = {0.f, 0.f, 0.f, 0.f};
  for (int m0 = 0; m0 < LATENT; m0 += 32) {
    {
      const float4 v = *reinterpret_cast<const float4*>(&wih0[(size_t)(i0 + r) * LATENT + m0 + c4]);
      As[r][c4] = v.x; As[r][c4 + 1] = v.y; As[r][c4 + 2] = v.z; As[r][c4 + 3] = v.w;
      const float4 w = *reinterpret_cast<const float4*>(&w2[(size_t)(m0 + r) * H + k0 + c4]);
      Bs[r][c4] = w.x; Bs[r][c4 + 1] = w.y; Bs[r][c4 + 2] = w.z; Bs[r][c4 + 3] = w.w;
    }
    __syncthreads();
    #pragma unroll
    for (int mm = 0; mm < 32; ++mm) {
      const float a = As[r][mm];
      #pragma unroll
      for (int x = 0; x < 4; ++x) acc[x] = fmaf(a, Bs[mm][c4 + x], acc[x]);
    }
    __syncthreads();
  }
  #pragma unroll
  for (int x = 0; x < 4; ++x) {
    uint_t u = __float_as_uint(acc[x]);
    wfh[(size_t)(i0 + r) * H + k0 + c4 + x] =
        (ushort_t)((u + 0x7FFFu + ((u >> 16) & 1u)) >> 16);
  }
}

// bf0[g] = bih0[g] + dot(wih0[g,:], bp2)
__global__ __launch_bounds__(256) void bias_fuse_kernel(const float* __restrict__ wih0,
                                                        const float* __restrict__ bp2,
                                                        const float* __restrict__ bih0,
                                                        float* __restrict__ bf0) {
  int g = blockIdx.x * blockDim.x + threadIdx.x;
  if (g < 3 * H) {
    float s = bih0[g];
    const float* row = wih0 + (size_t)g * LATENT;
    #pragma unroll 4
    for (int l = 0; l < LATENT; ++l) s = fmaf(row[l], bp2[l], s);
    bf0[g] = s;
  }
}

__device__ __forceinline__ float sigmoidf_(float v) { return 1.0f / (1.0f + expf(-v)); }

// ---------------- hierarchical grid barrier (acq-rel, known-good) ----------------
__device__ __forceinline__ void grid_barrier(unsigned* bar, int tid, int bid) {
  __syncthreads();
  if (tid == 0) {
    const int g = bid & 7;
    unsigned* arr    = bar + (g << 6);
    unsigned* rel    = bar + 1024 + (g << 6);
    unsigned* master = bar + 2048;
    unsigned gen = __hip_atomic_load(rel, __ATOMIC_RELAXED, __HIP_MEMORY_SCOPE_AGENT);
    unsigned a = __hip_atomic_fetch_add(arr, 1u, __ATOMIC_ACQ_REL, __HIP_MEMORY_SCOPE_AGENT);
    if (a == 31u) {
      __hip_atomic_store(arr, 0u, __ATOMIC_RELAXED, __HIP_MEMORY_SCOPE_AGENT);
      unsigned m = __hip_atomic_fetch_add(master, 1u, __ATOMIC_ACQ_REL, __HIP_MEMORY_SCOPE_AGENT);
      if (m == 7u) {
        __hip_atomic_store(master, 0u, __ATOMIC_RELAXED, __HIP_MEMORY_SCOPE_AGENT);
        #pragma unroll
        for (int i = 0; i < 8; ++i)
          __hip_atomic_fetch_add(bar + 1024 + (i << 6), 1u, __ATOMIC_ACQ_REL, __HIP_MEMORY_SCOPE_AGENT);
      }
    }
    while (__hip_atomic_load(rel, __ATOMIC_RELAXED, __HIP_MEMORY_SCOPE_AGENT) == gen)
      __builtin_amdgcn_s_sleep(1);
    (void)__hip_atomic_load(rel, __ATOMIC_ACQUIRE, __HIP_MEMORY_SCOPE_AGENT);
  }
  __syncthreads();
}

#define WAIT_VM(N) asm volatile("s_waitcnt vmcnt(" #N ")" ::: "memory")

// ---------------- one GEMM phase: counted-vmcnt ring pipeline ----------------
// RING=3 (r18 schedule: 2 barriers + lgkm per chunk) or RING=4 (1 barrier per
// chunk: issue(c+3) right after chunk-c barrier overwrites slot (c-1)%4, whose
// reads all waves provably completed before that barrier).
template <int NJ, int NG, int PH, int EPI, int RING>
__device__ __forceinline__ void phase_mm(
    char* smem, const int tid, const int Mb, const int jb, const bool active,
    const ushort_t* aAh, const ushort_t* aAl, int aApitch, int K1,
    const ushort_t* wAh,
    const ushort_t* aBh, const ushort_t* aBl, int aBpitch, int K2,
    const ushort_t* wBh,
    const float* bih, const float* bhh,
    const float* h_prev, float* h_out,
    ushort_t* out_hi, ushort_t* out_lo, int split_pitch,
    const float* bias, float* out_f32)
{
  if (!active) return;
  constexpr int NW = NJ * NG;
  constexpr int NSLOT = 4 + NW;          // A hi(2)+lo(2) + W(NW); 4KB slots
  constexpr int BUFB = NSLOT * 4096;
  constexpr int NPG = PH * NW;
  constexpr int CW = NJ * 16;

  const int b0 = Mb * 32;
  const int j0 = jb * CW;
  const int NC1 = K1 >> 7;
  const int NC2 = (PH == 2) ? (K2 >> 7) : 0;
  const int NC = NC1 + NC2;

  const char* g[NSLOT];
  auto build = [&](const ushort_t* ah, const ushort_t* al, int apitch,
                   const ushort_t* wh, int K) {
    const int rowt = tid >> 4;
    const int cp = tid & 15;
    const int cc = cp ^ rowt;
    #pragma unroll
    for (int u = 0; u < NSLOT; ++u) {
      const ushort_t* basep; size_t off;
      if (u < 2)      { basep = ah; off = (size_t)(b0 + u * 16 + rowt) * apitch + cc * 8; }
      else if (u < 4) { basep = al; off = (size_t)(b0 + (u - 2) * 16 + rowt) * apitch + cc * 8; }
      else {
        const int w = u - 4, jt = w % NJ, gate = w / NJ;
        const int wrow = (NG == 3) ? (gate * H + j0 + jt * 16 + rowt) : (j0 + jt * 16 + rowt);
        basep = wh; off = (size_t)wrow * K + cc * 8;
      }
      g[u] = (const char*)(basep + off);
    }
  };
  build(aAh, aAl, aApitch, wAh, K1);

  const int s = tid >> 6;
  const int q = (tid >> 4) & 3;
  const int r = tid & 15;
  const int gs = (((4 * s + q) ^ r) << 4);
  const int offA00 = r * 256 + gs;
  const int offA01 = 4096 + r * 256 + gs;
  const int offA10 = 8192 + r * 256 + gs;
  const int offA11 = 12288 + r * 256 + gs;
  int offW[NW];
  #pragma unroll
  for (int w = 0; w < NW; ++w) offW[w] = (4 + w) * 4096 + r * 256 + gs;

  f32x4 accA[NJ][NG][2];
  f32x4 accB[NJ][NG][2];
  #pragma unroll
  for (int jt = 0; jt < NJ; ++jt)
    #pragma unroll
    for (int gg = 0; gg < NG; ++gg)
      #pragma unroll
      for (int mf = 0; mf < 2; ++mf) {
        accA[jt][gg][mf] = (f32x4){0.f, 0.f, 0.f, 0.f};
        accB[jt][gg][mf] = (f32x4){0.f, 0.f, 0.f, 0.f};
      }

  const unsigned wofs = (unsigned)(tid >> 6) * 1024;
  auto issue = [&](int cc2) {
    const bool isB = (PH == 2) && (cc2 >= NC1);
    const int koff = (isB ? (cc2 - NC1) : cc2) * 256;
    char* dst = smem + (cc2 % RING) * BUFB + wofs;
    #pragma unroll
    for (int u = 0; u < NSLOT; ++u)
      __builtin_amdgcn_global_load_lds(
          (const AS1 void*)(g[u] + koff),
          (AS3 void*)(dst + u * 4096), 16, 0, 0);
  };

  auto compute = [&](int slot, f32x4 (&acc)[NJ][NG][2]) {
    const char* base = smem + slot * BUFB;
    bf16x8 ah0 = *(const bf16x8*)(base + offA00);
    bf16x8 ah1 = *(const bf16x8*)(base + offA01);
    bf16x8 al0 = *(const bf16x8*)(base + offA10);
    bf16x8 al1 = *(const bf16x8*)(base + offA11);
    #pragma unroll
    for (int gg = 0; gg < NG; ++gg)
      #pragma unroll
      for (int jt = 0; jt < NJ; ++jt) {
        const int w = gg * NJ + jt;
        bf16x8 wh = *(const bf16x8*)(base + offW[w]);
        acc[jt][gg][0] = __builtin_amdgcn_mfma_f32_16x16x32_bf16(ah0, wh, acc[jt][gg][0], 0, 0, 0);
        acc[jt][gg][0] = __builtin_amdgcn_mfma_f32_16x16x32_bf16(al0, wh, acc[jt][gg][0], 0, 0, 0);
        acc[jt][gg][1] = __builtin_amdgcn_mfma_f32_16x16x32_bf16(ah1, wh, acc[jt][gg][1], 0, 0, 0);
        acc[jt][gg][1] = __builtin_amdgcn_mfma_f32_16x16x32_bf16(al1, wh, acc[jt][gg][1], 0, 0, 0);
      }
  };

  // prologue: 3 chunks in flight
  issue(0);
  if (NC > 1) issue(1);
  if (NC > 2) issue(2);

  #pragma unroll 1
  for (int c = 0; c < NC; ++c) {
    {
      const int rem = NC - 1 - c;   // chunks in flight beyond c
      if (rem <= 0) {
        WAIT_VM(0);
      } else if (rem == 1) {
        if constexpr (NSLOT == 10)      WAIT_VM(10);
        else if constexpr (NSLOT == 7)  WAIT_VM(7);
        else if constexpr (NSLOT == 6)  WAIT_VM(6);
        else                            WAIT_VM(5);
      } else {
        if constexpr (NSLOT == 10)      WAIT_VM(20);
        else if constexpr (NSLOT == 7)  WAIT_VM(14);
        else if constexpr (NSLOT == 6)  WAIT_VM(12);
        else                            WAIT_VM(10);
      }
    }
    __builtin_amdgcn_s_barrier();        // chunk c visible; all waves past compute(c-1)
    if constexpr (RING == 4) {
      // single-barrier schedule: overwrite slot (c+3)%4 == (c-1)%4, whose reads
      // completed before this barrier. Issue BEFORE compute.
      if (c + 3 < NC) {
        if (PH == 2 && c + 3 == NC1) build(aBh, aBl, aBpitch, wBh, K2);
        issue(c + 3);
      }
      if (PH == 1 || c < NC1) compute(c % RING, accA);
      else                    compute(c % RING, accB);
    } else {
      if (PH == 1 || c < NC1) compute(c % RING, accA);
      else                    compute(c % RING, accB);
      if (c + 3 < NC) {
        asm volatile("s_waitcnt lgkmcnt(0)" ::: "memory");
        __builtin_amdgcn_s_barrier();
        if (PH == 2 && c + 3 == NC1) build(aBh, aBl, aBpitch, wBh, K2);
        issue(c + 3);
      }
    }
  }
  __syncthreads();

  // ---- cross-wave reduce (alias smem) ----
  const int lane = tid & 63;
  #pragma unroll
  for (int gg = 0; gg < NG; ++gg)
    #pragma unroll
    for (int jt = 0; jt < NJ; ++jt)
      #pragma unroll
      for (int mf = 0; mf < 2; ++mf) {
        const int w = gg * NJ + jt;
        *(f32x4*)(smem + (size_t)(((s * NPG + w) * 2 + mf) * 64 + lane) * 16) = accA[jt][gg][mf];
        if (PH == 2)
          *(f32x4*)(smem + (size_t)(((s * NPG + NW + w) * 2 + mf) * 64 + lane) * 16) = accB[jt][gg][mf];
      }
  __syncthreads();

  for (int o = tid; o < 32 * CW; o += 256) {
    const int row = o / CW, c = o % CW;
    const int jt = c >> 4, cr = c & 15;
    const int mf = row >> 4, br = row & 15, qq = br >> 2, rg = br & 3;
    const int ln = cr + qq * 16;
    float v[PH * NG];
    #pragma unroll
    for (int pg = 0; pg < PH * NG; ++pg) {
      const int w = (pg < NG) ? (pg * NJ + jt) : (NW + (pg - NG) * NJ + jt);
      float sum = 0.f;
      #pragma unroll
      for (int ss = 0; ss < 4; ++ss)
        sum += *(const float*)(smem + (size_t)(((ss * NPG + w) * 2 + mf) * 64 + ln) * 16 + rg * 4);
      v[pg] = sum;
    }
    const int bglob = b0 + row, jglob = j0 + c;
    if (EPI == 0) {
      float ir = v[0] + bih[jglob];
      float iz = v[1] + bih[H + jglob];
      float in_ = v[2] + bih[2 * H + jglob];
      float hr = v[3] + bhh[jglob];
      float hz = v[4] + bhh[H + jglob];
      float hn = v[5] + bhh[2 * H + jglob];
      float rr_ = sigmoidf_(ir + hr);
      float zz_ = sigmoidf_(iz + hz);
      float nn_ = tanhf(in_ + rr_ * hn);
      float hp = h_prev[(size_t)bglob * H + jglob];
      float ho = (1.f - zz_) * nn_ + zz_ * hp;
      h_out[(size_t)bglob * H + jglob] = ho;
      ushort_t hb, lb;
      split_bf16(ho, hb, lb);
      out_hi[(size_t)bglob * H + jglob] = hb;
      out_lo[(size_t)bglob * H + jglob] = lb;
    } else if (EPI == 1) {
      float vv = v[0] + bias[jglob];
      vv = fmaxf(vv, 0.f);
      ushort_t hb, lb;
      split_bf16(vv, hb, lb);
      out_hi[(size_t)bglob * split_pitch + jglob] = hb;
      out_lo[(size_t)bglob * split_pitch + jglob] = lb;
    } else {
      float vv = v[0] + bias[jglob];
      const int tt = bglob >> 7, bb2 = bglob & 127;
      out_f32[((size_t)bb2 * split_pitch + tt) * LATENT + jglob] = vv;
    }
  }
  __syncthreads();
}

// ---------------- persistent kernel: 65 enc + 192 dec phases, XCD-clustered ----------------

struct PParams {
  const ushort_t *ctxh, *ctxl;
  const ushort_t *wih0h, *whh0h;
  const ushort_t *wih1h, *whh1h;
  const ushort_t *w1h;
  const ushort_t *wfh;
  const float *bih0, *bhh0, *bih1, *bhh1, *bp1;
  const float *bf0;
  float *h0f0, *h0f1, *h1f0, *h1f1;
  ushort_t *h0hi0, *h0lo0, *h0hi1, *h0lo1;
  ushort_t *h1hi0, *h1lo0, *h1hi1, *h1lo1;
  ushort_t *h0Ahi, *h0Alo;      // [T_in][B][H]; aliased as pA in decoder
  unsigned* bar;
  int T_in, n_pred, ctx_pitch;
};

__global__ __launch_bounds__(256, 1) void gru_persistent(PParams P) {
  __shared__ char smem[122880];   // enc: 3x40KB ring; dec: 4x28KB ring = 112KB
  const int tid = threadIdx.x;
  const int bid = blockIdx.x;

  float* h0f[2] = {P.h0f0, P.h0f1};
  float* h1f[2] = {P.h1f0, P.h1f1};
  ushort_t* h0hi[2] = {P.h0hi0, P.h0hi1};
  ushort_t* h0lo[2] = {P.h0lo0, P.h0lo1};
  ushort_t* h1hi[2] = {P.h1hi0, P.h1hi1};
  ushort_t* h1lo[2] = {P.h1lo0, P.h1lo1};

  int p0 = 0, p1 = 0;

  // -------- pipelined encoder: L0 (blocks 0-127) || L1 (128-255), XCD-clustered --------
  const int idx = (bid < 128) ? bid : (bid - 128);
  const int eMb = (idx >> 5) & 3;
  const int ejb = (idx & 7) * 4 + ((idx >> 3) & 3);
  #pragma unroll 1
  for (int p = 0; p <= P.T_in; ++p) {
    const int n0 = p0 ^ 1, n1 = p1 ^ 1;
    if (bid < 128) {
      if (p < P.T_in) {
        const int t = p;
        phase_mm<2, 3, 2, 0, 3>(smem, tid, eMb, ejb, true,
            P.ctxh + (size_t)t * LATENT, P.ctxl + (size_t)t * LATENT, P.ctx_pitch, LATENT,
            P.wih0h,
            (t == 0) ? P.h0hi0 : P.h0Ahi + (size_t)(t - 1) * BH,
            (t == 0) ? P.h0lo0 : P.h0Alo + (size_t)(t - 1) * BH, H, H, P.whh0h,
            P.bih0, P.bhh0, h0f[p0], h0f[n0],
            P.h0Ahi + (size_t)t * BH, P.h0Alo + (size_t)t * BH, H, nullptr, nullptr);
      }
    } else {
      if (p >= 1) {
        const int t = p - 1;
        phase_mm<2, 3, 2, 0, 3>(smem, tid, eMb, ejb, true,
            P.h0Ahi + (size_t)t * BH, P.h0Alo + (size_t)t * BH, H, H,
            P.wih1h,
            h1hi[p1], h1lo[p1], H, H, P.whh1h,
            P.bih1, P.bhh1, h1f[p1], h1f[n1],
            h1hi[n1], h1lo[n1], H, nullptr, nullptr);
      }
    }
    grid_barrier(P.bar, tid, bid);
    if (p < P.T_in) p0 = n0;
    if (p >= 1) p1 = n1;
  }

  // -------- decoder: {D0 fused, D1, DP}, XCD-clustered, RING=4 single-barrier --------
  const int dMb = (bid >> 6) & 3;
  const int djb = (bid & 7) * 8 + ((bid >> 3) & 7);
  const ushort_t* d0ph = P.h0Ahi + (size_t)(P.T_in - 1) * BH;
  const ushort_t* d0pl = P.h0Alo + (size_t)(P.T_in - 1) * BH;
  ushort_t* pAh = P.h0Ahi;
  ushort_t* pAl = P.h0Alo;
  #pragma unroll 1
  for (int t = 0; t < P.n_pred; ++t) {
    const int n0 = p0 ^ 1;
    if (t == 0) {
      phase_mm<1, 3, 2, 0, 4>(smem, tid, dMb, djb, true,
          P.ctxh + (size_t)(P.T_in - 1) * LATENT, P.ctxl + (size_t)(P.T_in - 1) * LATENT,
          P.ctx_pitch, LATENT,
          P.wih0h,
          d0ph, d0pl, H, H, P.whh0h,
          P.bih0, P.bhh0, h0f[p0], h0f[n0], h0hi[n0], h0lo[n0], H, nullptr, nullptr);
    } else {
      phase_mm<1, 3, 2, 0, 4>(smem, tid, dMb, djb, true,
          pAh + (size_t)(t - 1) * BH, pAl + (size_t)(t - 1) * BH, H, H,
          P.wfh,
          d0ph, d0pl, H, H, P.whh0h,
          P.bf0, P.bhh0, h0f[p0], h0f[n0], h0hi[n0], h0lo[n0], H, nullptr, nullptr);
    }
    grid_barrier(P.bar, tid, bid);
    d0ph = h0hi[n0]; d0pl = h0lo[n0];
    const int n1 = p1 ^ 1;
    phase_mm<1, 3, 2, 0, 4>(smem, tid, dMb, djb, true,
        h0hi[n0], h0lo[n0], H, H,
        P.wih1h,
        h1hi[p1], h1lo[p1], H, H, P.whh1h,
        P.bih1, P.bhh1, h1f[p1], h1f[n1], h1hi[n1], h1lo[n1], H, nullptr, nullptr);
    grid_barrier(P.bar, tid, bid);
    phase_mm<1, 1, 1, 1, 4>(smem, tid, dMb, djb, true,
        h1hi[n1], h1lo[n1], H, H,
        P.w1h,
        nullptr, nullptr, 0, 0, nullptr,
        nullptr, nullptr, nullptr, nullptr,
        pAh + (size_t)t * BH, pAl + (size_t)t * BH, H, P.bp1, nullptr);
    grid_barrier(P.bar, tid, bid);
    p0 = n0; p1 = n1;
  }
}

// ---------------- final ys GEMM (parallel, RING=3) ----------------
__global__ __launch_bounds__(256, 2) void proj_out_kernel(
    const ushort_t* __restrict__ pAh, const ushort_t* __restrict__ pAl,
    const ushort_t* __restrict__ w2h, const float* __restrict__ bp2,
    float* __restrict__ out, int n_pred)
{
  __shared__ char smem[73728];   // 3-ring x 24KB (NSLOT=6)
  const int tid = threadIdx.x;
  const int rt = blockIdx.x >> 4;
  const int ct = blockIdx.x & 15;
  phase_mm<2, 1, 1, 3, 3>(smem, tid, rt, ct, true,
      pAh, pAl, H, H,
      w2h,
      nullptr, nullptr, 0, 0, nullptr,
      nullptr, nullptr, nullptr, nullptr,
      nullptr, nullptr, n_pred, bp2, out);
}

// ---------------- fp32 fallback (round-1, known-good) ----------------

__global__ __launch_bounds__(256) void gru_cell_kernel(
    const float* __restrict__ x, int xs, int Kih,
    const float* __restrict__ h_prev,
    const float* __restrict__ wih, const float* __restrict__ whh,
    const float* __restrict__ bih, const float* __restrict__ bhh,
    float* __restrict__ h_out)
{
  __shared__ float Xs[32][33];
  __shared__ float Ws[48][33];
  const int tid = threadIdx.x;
  const int b0 = blockIdx.x * 32;
  const int j0 = blockIdx.y * 16;
  const int bg = tid & 15;
  const int jj = tid >> 4;
  const int j = j0 + jj;
  float accA[2][3];
  float accB[2][3];
  #pragma unroll
  for (int g = 0; g < 3; ++g) {
    const float bi = bih[g * H + j];
    const float bh = bhh[g * H + j];
    accA[0][g] = bi; accA[1][g] = bi;
    accB[0][g] = bh; accB[1][g] = bh;
  }
  for (int k0 = 0; k0 < Kih; k0 += 32) {
    {
      const int rr = tid >> 3, c4 = (tid & 7) << 2;
      const float4 v = *reinterpret_cast<const float4*>(&x[(size_t)(b0 + rr) * xs + k0 + c4]);
      Xs[rr][c4 + 0] = v.x; Xs[rr][c4 + 1] = v.y; Xs[rr][c4 + 2] = v.z; Xs[rr][c4 + 3] = v.w;
    }
    for (int li = tid; li < 48 * 8; li += 256) {
      const int rr = li >> 3, c4 = (li & 7) << 2;
      const int g = rr >> 4, jr = rr & 15;
      const float4 v = *reinterpret_cast<const float4*>(&wih[(size_t)(g * H + j0 + jr) * Kih + k0 + c4]);
      Ws[rr][c4 + 0] = v.x; Ws[rr][c4 + 1] = v.y; Ws[rr][c4 + 2] = v.z; Ws[rr][c4 + 3] = v.w;
    }
    __syncthreads();
    #pragma unroll
    for (int k = 0; k < 32; ++k) {
      const float x0 = Xs[bg][k];
      const float x1 = Xs[bg + 16][k];
      #pragma unroll
      for (int g = 0; g < 3; ++g) {
        const float wv = Ws[g * 16 + jj][k];
        accA[0][g] = fmaf(x0, wv, accA[0][g]);
        accA[1][g] = fmaf(x1, wv, accA[1][g]);
      }
    }
    __syncthreads();
  }
  for (int k0 = 0; k0 < H; k0 += 32) {
    {
      const int rr = tid >> 3, c4 = (tid & 7) << 2;
      const float4 v = *reinterpret_cast<const float4*>(&h_prev[(size_t)(b0 + rr) * H + k0 + c4]);
      Xs[rr][c4 + 0] = v.x; Xs[rr][c4 + 1] = v.y; Xs[rr][c4 + 2] = v.z; Xs[rr][c4 + 3] = v.w;
    }
    for (int li = tid; li < 48 * 8; li += 256) {
      const int rr = li >> 3, c4 = (li & 7) << 2;
      const int g = rr >> 4, jr = rr & 15;
      const float4 v = *reinterpret_cast<const float4*>(&whh[(size_t)(g * H + j0 + jr) * H + k0 + c4]);
      Ws[rr][c4 + 0] = v.x; Ws[rr][c4 + 1] = v.y; Ws[rr][c4 + 2] = v.z; Ws[rr][c4 + 3] = v.w;
    }
    __syncthreads();
    #pragma unroll
    for (int k = 0; k < 32; ++k) {
      const float h0v = Xs[bg][k];
      const float h1v = Xs[bg + 16][k];
      #pragma unroll
      for (int g = 0; g < 3; ++g) {
        const float wv = Ws[g * 16 + jj][k];
        accB[0][g] = fmaf(h0v, wv, accB[0][g]);
        accB[1][g] = fmaf(h1v, wv, accB[1][g]);
      }
    }
    __syncthreads();
  }
  #pragma unroll
  for (int i = 0; i < 2; ++i) {
    const int b = b0 + bg + i * 16;
    const float hp = h_prev[(size_t)b * H + j];
    const float r = sigmoidf_(accA[i][0] + accB[i][0]);
    const float z = sigmoidf_(accA[i][1] + accB[i][1]);
    const float n = tanhf(accA[i][2] + r * accB[i][2]);
    h_out[(size_t)b * H + j] = (1.0f - z) * n + z * hp;
  }
}

__global__ __launch_bounds__(256) void gemm_bias_kernel(
    const float* __restrict__ X, int xs, int K,
    const float* __restrict__ W, const float* __restrict__ bias,
    float* __restrict__ out1, int o1s,
    float* __restrict__ out2, int o2s,
    int relu)
{
  __shared__ float Xs[32][33];
  __shared__ float Ws[16][33];
  const int tid = threadIdx.x;
  const int b0 = blockIdx.x * 32;
  const int n0 = blockIdx.y * 16;
  const int bg = tid & 15;
  const int nn = tid >> 4;
  const int n = n0 + nn;
  float acc0 = bias[n];
  float acc1 = acc0;
  for (int k0 = 0; k0 < K; k0 += 32) {
    {
      const int rr = tid >> 3, c4 = (tid & 7) << 2;
      const float4 v = *reinterpret_cast<const float4*>(&X[(size_t)(b0 + rr) * xs + k0 + c4]);
      Xs[rr][c4 + 0] = v.x; Xs[rr][c4 + 1] = v.y; Xs[rr][c4 + 2] = v.z; Xs[rr][c4 + 3] = v.w;
    }
    if (tid < 128) {
      const int rr = tid >> 3, c4 = (tid & 7) << 2;
      const float4 v = *reinterpret_cast<const float4*>(&W[(size_t)(n0 + rr) * K + k0 + c4]);
      Ws[rr][c4 + 0] = v.x; Ws[rr][c4 + 1] = v.y; Ws[rr][c4 + 2] = v.z; Ws[rr][c4 + 3] = v.w;
    }
    __syncthreads();
    #pragma unroll
    for (int k = 0; k < 32; ++k) {
      const float wv = Ws[nn][k];
      acc0 = fmaf(Xs[bg][k], wv, acc0);
      acc1 = fmaf(Xs[bg + 16][k], wv, acc1);
    }
    __syncthreads();
  }
  if (relu) { acc0 = fmaxf(acc0, 0.0f); acc1 = fmaxf(acc1, 0.0f); }
  const int ba = b0 + bg, bb = b0 + bg + 16;
  out1[(size_t)ba * o1s + n] = acc0;
  out1[(size_t)bb * o1s + n] = acc1;
  if (out2 != nullptr) {
    out2[(size_t)ba * o2s + n] = acc0;
    out2[(size_t)bb * o2s + n] = acc1;
  }
}

// ---------------- host launch ----------------

extern "C" void kernel_launch(void* const* d_in, const int* in_sizes, int n_in,
                              void* d_out, int out_size, void* d_ws, size_t ws_size,
                              hipStream_t stream) {
  (void)n_in;
  const float* ctx  = (const float*)d_in[0];
  const float* wih0 = (const float*)d_in[1];
  const float* whh0 = (const float*)d_in[2];
  const float* bih0 = (const float*)d_in[3];
  const float* bhh0 = (const float*)d_in[4];
  const float* wih1 = (const float*)d_in[5];
  const float* whh1 = (const float*)d_in[6];
  const float* bih1 = (const float*)d_in[7];
  const float* bhh1 = (const float*)d_in[8];
  const float* w1   = (const float*)d_in[9];
  const float* bp1  = (const float*)d_in[10];
  const float* w2   = (const float*)d_in[11];
  const float* bp2  = (const float*)d_in[12];

  const int T_in   = in_sizes[0] / (B * LATENT);
  const int n_pred = out_size / (B * LATENT);
  float* out = (float*)d_out;

  // ---- ws layout ----
  size_t cur = 0;
  auto alloc = [&](size_t bytes) -> void* {
    void* p = (char*)d_ws + cur;
    cur += (bytes + 255) & ~(size_t)255;
    return p;
  };
  const int E_wih0 = 3 * H * LATENT, E_whh0 = 3 * H * H;
  const int E_wih1 = 3 * H * H, E_whh1 = 3 * H * H;
  const int E_w1 = H * H, E_w2 = LATENT * H;
  const int E_wf = 3 * H * H;
  const int E_ctx = in_sizes[0];

  ushort_t* wih0h = (ushort_t*)alloc(E_wih0 * 2);
  ushort_t* whh0h = (ushort_t*)alloc(E_whh0 * 2);
  ushort_t* wih1h = (ushort_t*)alloc(E_wih1 * 2);
  ushort_t* whh1h = (ushort_t*)alloc(E_whh1 * 2);
  ushort_t* w1h   = (ushort_t*)alloc(E_w1 * 2);
  ushort_t* w2h   = (ushort_t*)alloc(E_w2 * 2);
  ushort_t* wfh   = (ushort_t*)alloc((size_t)E_wf * 2);
  ushort_t* ctxh  = (ushort_t*)alloc((size_t)E_ctx * 2);
  ushort_t* ctxl  = (ushort_t*)alloc((size_t)E_ctx * 2);
  ushort_t* h0Ahi = (ushort_t*)alloc((size_t)T_in * BH * 2);
  ushort_t* h0Alo = (ushort_t*)alloc((size_t)T_in * BH * 2);
  float* bf0 = (float*)alloc(3 * H * 4);
  size_t zero_start = cur;
  float* h0f[2]; float* h1f[2];
  ushort_t* h0hi[2]; ushort_t* h0lo[2]; ushort_t* h1hi[2]; ushort_t* h1lo[2];
  h0f[0] = (float*)alloc(BH * 4); h0f[1] = (float*)alloc(BH * 4);
  h1f[0] = (float*)alloc(BH * 4); h1f[1] = (float*)alloc(BH * 4);
  h0hi[0] = (ushort_t*)alloc(BH * 2); h0lo[0] = (ushort_t*)alloc(BH * 2);
  h0hi[1] = (ushort_t*)alloc(BH * 2); h0lo[1] = (ushort_t*)alloc(BH * 2);
  h1hi[0] = (ushort_t*)alloc(BH * 2); h1lo[0] = (ushort_t*)alloc(BH * 2);
  h1hi[1] = (ushort_t*)alloc(BH * 2); h1lo[1] = (ushort_t*)alloc(BH * 2);
  unsigned* bar = (unsigned*)alloc(16384);
  size_t zero_bytes = cur - zero_start;
  size_t required = cur;

  if (ws_size >= required && n_pred <= T_in) {
    auto splitA = [&](const float* s, ushort_t* hi, ushort_t* lo, int n) {
      int blocks = (n + 255) / 256; if (blocks > 2048) blocks = 2048;
      split_kernel<<<blocks, 256, 0, stream>>>(s, hi, lo, n);
    };
    auto splitW = [&](const float* s, ushort_t* hi, int n) {
      int blocks = (n + 255) / 256; if (blocks > 2048) blocks = 2048;
      split_hi_kernel<<<blocks, 256, 0, stream>>>(s, hi, n);
    };
    splitW(wih0, wih0h, E_wih0);
    splitW(whh0, whh0h, E_whh0);
    splitW(wih1, wih1h, E_wih1);
    splitW(whh1, whh1h, E_whh1);
    splitW(w1, w1h, E_w1);
    splitW(w2, w2h, E_w2);
    wf_kernel<<<dim3(3 * H / 32, H / 32), 256, 0, stream>>>(wih0, w2, wfh);
    bias_fuse_kernel<<<(3 * H + 255) / 256, 256, 0, stream>>>(wih0, bp2, bih0, bf0);
    splitA(ctx, ctxh, ctxl, E_ctx);
    {
      int n4 = (int)(zero_bytes / 16);
      zero4_kernel<<<2048, 256, 0, stream>>>((float4*)((char*)d_ws + zero_start), n4);
    }

    PParams P;
    P.ctxh = ctxh; P.ctxl = ctxl;
    P.wih0h = wih0h; P.whh0h = whh0h;
    P.wih1h = wih1h; P.whh1h = whh1h;
    P.w1h = w1h; P.wfh = wfh;
    P.bih0 = bih0; P.bhh0 = bhh0; P.bih1 = bih1; P.bhh1 = bhh1; P.bp1 = bp1;
    P.bf0 = bf0;
    P.h0f0 = h0f[0]; P.h0f1 = h0f[1]; P.h1f0 = h1f[0]; P.h1f1 = h1f[1];
    P.h0hi0 = h0hi[0]; P.h0lo0 = h0lo[0]; P.h0hi1 = h0hi[1]; P.h0lo1 = h0lo[1];
    P.h1hi0 = h1hi[0]; P.h1lo0 = h1lo[0]; P.h1hi1 = h1hi[1]; P.h1lo1 = h1lo[1];
    P.h0Ahi = h0Ahi; P.h0Alo = h0Alo;
    P.bar = bar;
    P.T_in = T_in; P.n_pred = n_pred; P.ctx_pitch = T_in * LATENT;

    gru_persistent<<<256, 256, 0, stream>>>(P);

    const int rowtiles = (n_pred * B) / 32;
    proj_out_kernel<<<rowtiles * 16, 256, 0, stream>>>(h0Ahi, h0Alo, w2h, bp2, out, n_pred);
    return;
  }

  // ---------- fp32 fallback path (round-1) ----------
  float* ws = (float*)d_ws;
  float* h0a = ws;
  float* h0b = h0a + (size_t)BH;
  float* h1a = h0b + (size_t)BH;
  float* h1b = h1a + (size_t)BH;
  float* p   = h1b + (size_t)BH;
  {
    int n4 = (4 * BH) / 4;
    zero4_kernel<<<256, 256, 0, stream>>>((float4*)h0a, n4);
  }
  float* y = p + (size_t)BH;
  float* h0p = h0a; float* h0n = h0b;
  float* h1p = h1a; float* h1n = h1b;
  const dim3 cgrid(4, 64);
  for (int t = 0; t < T_in; ++t) {
    const float* x = ctx + (size_t)t * LATENT;
    gru_cell_kernel<<<cgrid, 256, 0, stream>>>(x, T_in * LATENT, LATENT,
                                               h0p, wih0, whh0, bih0, bhh0, h0n);
    gru_cell_kernel<<<cgrid, 256, 0, stream>>>(h0n, H, H,
                                               h1p, wih1, whh1, bih1, bhh1, h1n);
    float* tmp;
    tmp = h0p; h0p = h0n; h0n = tmp;
    tmp = h1p; h1p = h1n; h1n = tmp;
  }
  for (int t = 0; t < n_pred; ++t) {
    const float* x; int xstride;
    if (t == 0) { x = ctx + (size_t)(T_in - 1) * LATENT; xstride = T_in * LATENT; }
    else        { x = y; xstride = LATENT; }
    gru_cell_kernel<<<cgrid, 256, 0, stream>>>(x, xstride, LATENT,
                                               h0p, wih0, whh0, bih0, bhh0, h0n);
    gru_cell_kernel<<<cgrid, 256, 0, stream>>>(h0n, H, H,
                                               h1p, wih1, whh1, bih1, bhh1, h1n);
    gemm_bias_kernel<<<dim3(4, H / 16), 256, 0, stream>>>(h1n, H, H, w1, bp1,
                                                          p, H, nullptr, 0, 1);
    gemm_bias_kernel<<<dim3(4, LATENT / 16), 256, 0, stream>>>(p, H, H, w2, bp2,
                                                               y, LATENT,
                                                               out + (size_t)t * LATENT,
                                                               n_pred * LATENT, 0);
    float* tmp;
    tmp = h0p; h0p = h0n; h0n = tmp;
    tmp = h1p; h1p = h1n; h1n = tmp;
  }
}